// Round 11
// baseline (1849.543 us; speedup 1.0000x reference)
//

#include <hip/hip_runtime.h>
#include <hip/hip_fp16.h>

typedef _Float16 half8 __attribute__((ext_vector_type(8)));
typedef float float4_ __attribute__((ext_vector_type(4)));

__device__ __forceinline__ float rcp_(float x) { return __builtin_amdgcn_rcpf(x); }
__device__ __forceinline__ float sigf(float x) { return rcp_(1.f + __expf(-x)); }
__device__ __forceinline__ float tanhf2(float x) {
  x = fminf(fmaxf(x, -15.f), 15.f);
  float e = __expf(-2.f * x);
  return (1.f - e) * rcp_(1.f + e);
}

// ---------------------------------------------------------------------------
// K1: 1088 independent small LSTMs (input dim 1, H=128), 16 seqs per block.
// R8 version (deferred result stores). Unchanged this round.
// ---------------------------------------------------------------------------
__global__ __launch_bounds__(512, 2)
void k1_lstm(const float* __restrict__ Y, const float* __restrict__ Xp,
             const float* __restrict__ Xn, const float* __restrict__ Xi,
             const float* __restrict__ Wih, const float* __restrict__ Whh,
             const float* __restrict__ bih, const float* __restrict__ bhh,
             _Float16* __restrict__ result)
{
  __shared__ float x_lds[16][513];
  __shared__ _Float16 hbuf[2][16][136];

  const int tid  = threadIdx.x;
  const int wv   = tid >> 6;       // wave 0..7
  const int lane = tid & 63;
  const int cl   = lane & 15;
  const int rowg = lane >> 4;      // 0..3
  const int bid  = blockIdx.x;

  const float* xsrc; int slot; int do_mean; int b_out_base;
  if (bid < 2)       { xsrc = Y  + (size_t)(bid * 16) * 512;        slot = 0; do_mean = 0; b_out_base = bid * 16; }
  else if (bid < 4)  { xsrc = Xi + (size_t)((bid - 2) * 16) * 512;  slot = 3; do_mean = 0; b_out_base = (bid - 2) * 16; }
  else if (bid < 36) { xsrc = Xp + (size_t)((bid - 4) * 16) * 512;  slot = 1; do_mean = 1; b_out_base = bid - 4; }
  else               { xsrc = Xn + (size_t)((bid - 36) * 16) * 512; slot = 2; do_mean = 1; b_out_base = bid - 36; }

  // stage x for all 16 sequences
  for (int i = tid; i < 16 * 512; i += 512) {
    int r = i >> 9, t = i & 511;
    x_lds[r][t] = xsrc[r * 512 + t];
  }
  // zero initial h buffer
  for (int i = tid; i < 16 * 136; i += 512) {
    hbuf[0][i / 136][i % 136] = (_Float16)0.f;
  }

  // persistent Whh fragments: gate g, this wave's gate-column cg
  const int cg = wv * 16 + cl;
  half8 bw[4][4];
  #pragma unroll
  for (int g = 0; g < 4; ++g) {
    #pragma unroll
    for (int kc = 0; kc < 4; ++kc) {
      const float* p = Whh + (size_t)(g * 128 + cg) * 128 + kc * 32 + rowg * 8;
      half8 v;
      #pragma unroll
      for (int j = 0; j < 8; ++j) v[j] = (_Float16)p[j];
      bw[g][kc] = v;
    }
  }
  float wih_r[4], bias_r[4];
  #pragma unroll
  for (int g = 0; g < 4; ++g) {
    wih_r[g]  = Wih[g * 128 + cg];
    bias_r[g] = bih[g * 128 + cg] + bhh[g * 128 + cg];
  }

  float c_reg[4] = {0.f, 0.f, 0.f, 0.f};
  float hvp[4] = {0.f, 0.f, 0.f, 0.f};   // deferred-store carry
  float sprev = 0.f;
  __syncthreads();

  for (int t = 0; t < 512; ++t) {
    // deferred global store of step t-1 (retires under this step's MFMA phase)
    if (t > 0) {
      if (!do_mean) {
        #pragma unroll
        for (int i = 0; i < 4; ++i) {
          int b = b_out_base + rowg * 4 + i;
          result[(((size_t)b * 512 + (t - 1)) * 4 + slot) * 128 + cg] = (_Float16)hvp[i];
        }
      } else {
        if (rowg == 0)
          result[(((size_t)b_out_base * 512 + (t - 1)) * 4 + slot) * 128 + cg] = (_Float16)sprev;
      }
    }

    const int cur = t & 1;
    half8 a[4];
    #pragma unroll
    for (int kc = 0; kc < 4; ++kc)
      a[kc] = *(const half8*)&hbuf[cur][cl][kc * 32 + rowg * 8];

    float4_ acc[4];
    #pragma unroll
    for (int g = 0; g < 4; ++g) {
      float4_ z = {0.f, 0.f, 0.f, 0.f};
      #pragma unroll
      for (int kc = 0; kc < 4; ++kc)
        z = __builtin_amdgcn_mfma_f32_16x16x32_f16(a[kc], bw[g][kc], z, 0, 0, 0);
      acc[g] = z;
    }

    float hv[4];
    #pragma unroll
    for (int i = 0; i < 4; ++i) {
      const int row = rowg * 4 + i;
      float x  = x_lds[row][t];
      float ui = acc[0][i] + x * wih_r[0] + bias_r[0];
      float uf = acc[1][i] + x * wih_r[1] + bias_r[1];
      float ug = acc[2][i] + x * wih_r[2] + bias_r[2];
      float uo = acc[3][i] + x * wih_r[3] + bias_r[3];
      float ii = sigf(ui), ff = sigf(uf), gg = tanhf2(ug), oo = sigf(uo);
      float c  = ff * c_reg[i] + ii * gg;
      c_reg[i] = c;
      float h  = oo * tanhf2(c);
      hv[i] = h;
      hbuf[cur ^ 1][row][cg] = (_Float16)h;
    }

    if (!do_mean) {
      #pragma unroll
      for (int i = 0; i < 4; ++i) hvp[i] = hv[i];
    } else {
      float s = hv[0] + hv[1] + hv[2] + hv[3];
      s += __shfl_xor(s, 16, 64);
      s += __shfl_xor(s, 32, 64);
      sprev = s * 0.0625f;
    }
    __syncthreads();
  }

  // final flush (t = 511)
  if (!do_mean) {
    #pragma unroll
    for (int i = 0; i < 4; ++i) {
      int b = b_out_base + rowg * 4 + i;
      result[(((size_t)b * 512 + 511) * 4 + slot) * 128 + cg] = (_Float16)hvp[i];
    }
  } else {
    if (rowg == 0)
      result[(((size_t)b_out_base * 512 + 511) * 4 + slot) * 128 + cg] = (_Float16)sprev;
  }
}

// ---------------------------------------------------------------------------
// K2: input-projection GEMMs for the Mi-LSTM scan (verbatim R1/R6).
// ---------------------------------------------------------------------------
__global__ __launch_bounds__(512, 2)
void k2_gemm(const _Float16* __restrict__ result,
             const float* __restrict__ Wc, const float* __restrict__ Wg,
             const float* __restrict__ Wf, const float* __restrict__ Wo,
             _Float16* __restrict__ candX, _Float16* __restrict__ igX,
             _Float16* __restrict__ fX, _Float16* __restrict__ oX)
{
  __shared__ _Float16 a_lds[128][136];
  __shared__ _Float16 bt_lds[256][136];

  const int tid   = threadIdx.x;
  const int lane  = tid & 63;
  const int wv    = tid >> 6;      // msub
  const int cl    = lane & 15, rowg = lane >> 4;
  const int mtile = blockIdx.x;    // 0..127
  const int role  = blockIdx.y;    // 0 or 1..4

  const int nchunks = (role == 0) ? 4 : 1;
  const int kstream = role - 1;

  float4_ acc[16];
  #pragma unroll
  for (int n = 0; n < 16; ++n) acc[n] = (float4_){0.f, 0.f, 0.f, 0.f};

  for (int ch = 0; ch < nchunks; ++ch) {
    const int koff = (role == 0) ? ch * 128 : kstream * 128;
    for (int i = tid; i < 1024; i += 512) {
      int r = i >> 3, v8 = i & 7;
      half8 val = *(const half8*)&result[((size_t)(mtile * 128 + r)) * 512 + koff + v8 * 8];
      *(half8*)&a_lds[r][v8 * 8] = val;
    }
    for (int i = tid; i < 128 * 256; i += 512) {
      int n = i & 255, kk = i >> 8;
      float w;
      if (role == 0) {
        w = (n < 128) ? Wf[(size_t)(ch * 128 + kk) * 128 + n]
                      : Wo[(size_t)(ch * 128 + kk) * 128 + (n - 128)];
      } else {
        w = (n < 128) ? Wc[(size_t)(kstream * 128 + kk) * 128 + n]
                      : Wg[(size_t)(kstream * 128 + kk) * 128 + (n - 128)];
      }
      bt_lds[n][kk] = (_Float16)w;
    }
    __syncthreads();
    #pragma unroll
    for (int kc = 0; kc < 4; ++kc) {
      half8 a = *(const half8*)&a_lds[wv * 16 + cl][kc * 32 + rowg * 8];
      #pragma unroll
      for (int n = 0; n < 16; ++n) {
        half8 bb = *(const half8*)&bt_lds[n * 16 + cl][kc * 32 + rowg * 8];
        acc[n] = __builtin_amdgcn_mfma_f32_16x16x32_f16(a, bb, acc[n], 0, 0, 0);
      }
    }
    __syncthreads();
  }

  #pragma unroll
  for (int n = 0; n < 16; ++n) {
    int col = n * 16 + cl;
    #pragma unroll
    for (int i = 0; i < 4; ++i) {
      size_t r = (size_t)mtile * 128 + wv * 16 + rowg * 4 + i;
      _Float16 v = (_Float16)acc[n][i];
      if (role == 0) {
        if (col < 128) fX[r * 128 + col] = v;
        else           oX[r * 128 + (col - 128)] = v;
      } else {
        if (col < 128) candX[(r * 4 + kstream) * 128 + col] = v;
        else           igX  [(r * 4 + kstream) * 128 + (col - 128)] = v;
      }
    }
  }
}

// ---------------------------------------------------------------------------
// K3: Mi-LSTM scan — MFMA dot phase. raw[1408] = U_all · h computed as 88
// column-groups of 16 via mfma_f32_16x16x32_f16: A = weight fragment (lane
// holds U[col=g*16+cl][k], k = kc*32+rowg*8+j — same gather as PRELOAD),
// B = h broadcast (lane reads hp4[kc*4+rowg]; identical across cl).
// D (m89 layout): lane cl==0 holds cols g*16+rowg*4+i -> one predicated
// ds_write_b128 per group. Weights/accs may live in AGPRs (MFMA sources
// them directly; no VALU copies). Groups 80..87 contract against c (cWa).
// Stage2/3, barriers, prefetch, deferred Y2 store: identical to R10.
// ---------------------------------------------------------------------------
__global__ __launch_bounds__(512, 1)
void k3_scan(const float* __restrict__ Uc, const float* __restrict__ Ug,
             const float* __restrict__ Uf, const float* __restrict__ Uo,
             const float* __restrict__ Wa,
             const float* __restrict__ bc, const float* __restrict__ bg,
             const float* __restrict__ bfv, const float* __restrict__ bov,
             const float* __restrict__ init_c, const float* __restrict__ init_h,
             const _Float16* __restrict__ candX, const _Float16* __restrict__ igX,
             const _Float16* __restrict__ fX, const _Float16* __restrict__ oX,
             _Float16* __restrict__ Y2)
{
  __shared__ __align__(16) unsigned h_pk[64];
  __shared__ __align__(16) unsigned c_pk[64];
  __shared__ float c_f32[128];
  __shared__ __align__(16) float raw[1408];
  __shared__ float part2[2][4];

  const int tid  = threadIdx.x;
  const int b    = blockIdx.x;
  const int wv   = tid >> 6;
  const int lane = tid & 63;
  const int cl   = lane & 15;
  const int rowg = lane >> 4;

  // gather weight A-fragments: 11 groups of 16 output-cols per wave
  half8 wfrag[11][4];
  #pragma unroll
  for (int gi = 0; gi < 11; ++gi) {
    const int col = (wv * 11 + gi) * 16 + cl;   // global slot 0..1407
    const float* src;
    if (col < 512)       src = Uc + (col >> 7) * 16384 + (col & 127);
    else if (col < 1024) src = Ug + ((col >> 7) - 4) * 16384 + (col & 127);
    else if (col < 1152) src = Uf + (col - 1024);
    else if (col < 1280) src = Uo + (col - 1152);
    else                 src = Wa + (col - 1280);
    #pragma unroll
    for (int kc = 0; kc < 4; ++kc) {
      half8 v;
      #pragma unroll
      for (int j = 0; j < 8; ++j)
        v[j] = (_Float16)src[(kc * 32 + rowg * 8 + j) * 128];
      wfrag[gi][kc] = v;
    }
  }

  float bc_r[4] = {0, 0, 0, 0}, bg_r[4] = {0, 0, 0, 0}, bf_r = 0.f, bo_r = 0.f;
  if (tid < 128) {
    #pragma unroll
    for (int k = 0; k < 4; ++k) { bc_r[k] = bc[k * 128 + tid]; bg_r[k] = bg[k * 128 + tid]; }
    bf_r = bfv[tid]; bo_r = bov[tid];
    c_f32[tid] = init_c[b * 128 + tid];
  }
  if (tid < 64) {
    union { _Float16 h[2]; unsigned u; } hp, cp;
    hp.h[0] = (_Float16)init_h[b * 128 + 2 * tid];
    hp.h[1] = (_Float16)init_h[b * 128 + 2 * tid + 1];
    cp.h[0] = (_Float16)init_c[b * 128 + 2 * tid];
    cp.h[1] = (_Float16)init_c[b * 128 + 2 * tid + 1];
    h_pk[tid] = hp.u;
    c_pk[tid] = cp.u;
  }
  __syncthreads();

  float hprev = 0.f;   // deferred Y2 carry (tid<128)

  for (int t = 0; t < 512; ++t) {
    // deferred Y2 store of step t-1 (retires under this step's MFMA phase)
    if (t > 0 && tid < 128)
      Y2[((size_t)b * 512 + (t - 1)) * 128 + tid] = (_Float16)hprev;

    // prefetch precomputed input projections (hidden under the MFMA phase)
    float cx[4] = {0, 0, 0, 0}, gx[4] = {0, 0, 0, 0}, fx = 0.f, ox = 0.f;
    if (tid < 128) {
      size_t r = (size_t)b * 512 + t;
      #pragma unroll
      for (int k = 0; k < 4; ++k) {
        cx[k] = (float)candX[(r * 4 + k) * 128 + tid];
        gx[k] = (float)igX  [(r * 4 + k) * 128 + tid];
      }
      fx = (float)fX[r * 128 + tid];
      ox = (float)oX[r * 128 + tid];
    }

    // MFMA phase: raw[g*16 .. g*16+15] = U_group_g · (h or c)
    {
      const uint4* hp4 = (const uint4*)h_pk;
      const uint4* cp4 = (const uint4*)c_pk;
      union { uint4 u; half8 h; } hb[4], cb[4];
      #pragma unroll
      for (int kc = 0; kc < 4; ++kc) {
        hb[kc].u = hp4[kc * 4 + rowg];
        cb[kc].u = cp4[kc * 4 + rowg];
      }
      #pragma unroll
      for (int gi = 0; gi < 11; ++gi) {
        const int g = wv * 11 + gi;
        float4_ acc = {0.f, 0.f, 0.f, 0.f};
        if (g < 80) {
          #pragma unroll
          for (int kc = 0; kc < 4; ++kc)
            acc = __builtin_amdgcn_mfma_f32_16x16x32_f16(wfrag[gi][kc], hb[kc].h, acc, 0, 0, 0);
        } else {
          #pragma unroll
          for (int kc = 0; kc < 4; ++kc)
            acc = __builtin_amdgcn_mfma_f32_16x16x32_f16(wfrag[gi][kc], cb[kc].h, acc, 0, 0, 0);
        }
        if (cl == 0)
          *(float4_*)&raw[g * 16 + rowg * 4] = acc;
      }
    }
    __syncthreads();   // B1

    float l0 = 0.f, l1 = 0.f, l2 = 0.f, l3 = 0.f, fj = 0.f, oj = 0.f;
    if (tid < 128) {
      float cand[4], ig[4];
      #pragma unroll
      for (int k = 0; k < 4; ++k) {
        float uc = cx[k] + raw[k * 128 + tid] + bc_r[k];
        float ui = gx[k] + raw[512 + k * 128 + tid] + bg_r[k];
        cand[k] = tanhf2(uc);
        ig[k]   = sigf(ui);
      }
      l0 = ig[0] * cand[0]; l1 = ig[1] * cand[1];
      l2 = ig[2] * cand[2]; l3 = ig[3] * cand[3];
      float cwa = raw[1280 + tid];
      float p0 = l0 * cwa, p1 = l1 * cwa, p2 = l2 * cwa, p3 = l3 * cwa;
      #pragma unroll
      for (int m = 1; m < 64; m <<= 1) {
        p0 += __shfl_xor(p0, m, 64);
        p1 += __shfl_xor(p1, m, 64);
        p2 += __shfl_xor(p2, m, 64);
        p3 += __shfl_xor(p3, m, 64);
      }
      if ((tid & 63) == 0) {
        part2[tid >> 6][0] = p0; part2[tid >> 6][1] = p1;
        part2[tid >> 6][2] = p2; part2[tid >> 6][3] = p3;
      }
      fj = sigf(fx + raw[1024 + tid] + bf_r);
      oj = sigf(ox + raw[1152 + tid] + bo_r);
    }
    __syncthreads();   // B2

    if (tid < 128) {
      float d0 = part2[0][0] + part2[1][0];
      float d1 = part2[0][1] + part2[1][1];
      float d2 = part2[0][2] + part2[1][2];
      float d3 = part2[0][3] + part2[1][3];
      float mx = fmaxf(fmaxf(d0, d1), fmaxf(d2, d3));
      float e0 = __expf(d0 - mx), e1 = __expf(d1 - mx);
      float e2 = __expf(d2 - mx), e3 = __expf(d3 - mx);
      float inv = rcp_(e0 + e1 + e2 + e3);
      float lmix = (e0 * l0 + e1 * l1 + e2 * l2 + e3 * l3) * inv;
      float c = fj * c_f32[tid] + lmix;
      c_f32[tid] = c;
      float h = oj * tanhf2(c);
      ((_Float16*)h_pk)[tid] = (_Float16)h;
      ((_Float16*)c_pk)[tid] = (_Float16)c;
      hprev = h;        // Y2 store deferred to next loop top
    }
    __syncthreads();   // B3
  }

  // final flush (t = 511)
  if (tid < 128)
    Y2[((size_t)b * 512 + 511) * 128 + tid] = (_Float16)hprev;
}

// ---------------------------------------------------------------------------
// K4: temporal attention + MLP head, one block per b (verbatim R1/R6).
// ---------------------------------------------------------------------------
__global__ __launch_bounds__(256, 1)
void k4_attn(const _Float16* __restrict__ Y2,
             const float* __restrict__ Watt, const float* __restrict__ batt,
             const float* __restrict__ vatt,
             const float* __restrict__ W1, const float* __restrict__ b1,
             const float* __restrict__ W2, const float* __restrict__ b2,
             const float* __restrict__ W3, const float* __restrict__ b3,
             float* __restrict__ out)
{
  __shared__ _Float16 wt_lds[128][136];
  __shared__ float sc[512];
  __shared__ float red[8];
  __shared__ float y3[128];
  __shared__ float hm[128];

  const int tid = threadIdx.x;
  const int b   = blockIdx.x;
  const int lane = tid & 63, wv = tid >> 6;
  const int cl = lane & 15, rowg = lane >> 4;

  for (int i = tid; i < 128 * 128; i += 256) {
    int h = i >> 7, j = i & 127;
    wt_lds[j][h] = (_Float16)Watt[h * 128 + j];
  }
  __syncthreads();

  half8 bw[8][4];
  #pragma unroll
  for (int n = 0; n < 8; ++n)
    #pragma unroll
    for (int kc = 0; kc < 4; ++kc)
      bw[n][kc] = *(const half8*)&wt_lds[n * 16 + cl][kc * 32 + rowg * 8];
  float battr[8], vattr[8];
  #pragma unroll
  for (int n = 0; n < 8; ++n) { battr[n] = batt[n * 16 + cl]; vattr[n] = vatt[n * 16 + cl]; }

  for (int mt = wv * 8; mt < wv * 8 + 8; ++mt) {
    half8 a[4];
    #pragma unroll
    for (int kc = 0; kc < 4; ++kc)
      a[kc] = *(const half8*)&Y2[((size_t)b * 512 + mt * 16 + cl) * 128 + kc * 32 + rowg * 8];
    float sp[4] = {0.f, 0.f, 0.f, 0.f};
    #pragma unroll
    for (int n = 0; n < 8; ++n) {
      float4_ acc = {0.f, 0.f, 0.f, 0.f};
      #pragma unroll
      for (int kc = 0; kc < 4; ++kc)
        acc = __builtin_amdgcn_mfma_f32_16x16x32_f16(a[kc], bw[n][kc], acc, 0, 0, 0);
      #pragma unroll
      for (int i = 0; i < 4; ++i)
        sp[i] += tanhf2(acc[i] + battr[n]) * vattr[n];
    }
    #pragma unroll
    for (int i = 0; i < 4; ++i) {
      #pragma unroll
      for (int m = 1; m < 16; m <<= 1) sp[i] += __shfl_xor(sp[i], m, 64);
    }
    if (cl == 0) {
      #pragma unroll
      for (int i = 0; i < 4; ++i) sc[mt * 16 + rowg * 4 + i] = sp[i];
    }
  }
  __syncthreads();

  // softmax over 512 scores
  float v0 = sc[tid], v1 = sc[tid + 256];
  float mx = fmaxf(v0, v1);
  #pragma unroll
  for (int m = 1; m < 64; m <<= 1) mx = fmaxf(mx, __shfl_xor(mx, m, 64));
  if (lane == 0) red[wv] = mx;
  __syncthreads();
  mx = fmaxf(fmaxf(red[0], red[1]), fmaxf(red[2], red[3]));
  float e0 = __expf(v0 - mx), e1 = __expf(v1 - mx);
  float s = e0 + e1;
  #pragma unroll
  for (int m = 1; m < 64; m <<= 1) s += __shfl_xor(s, m, 64);
  __syncthreads();
  if (lane == 0) red[wv] = s;
  __syncthreads();
  float inv = rcp_(red[0] + red[1] + red[2] + red[3]);
  sc[tid] = e0 * inv;
  sc[tid + 256] = e1 * inv;
  __syncthreads();

  // Y3 = attw @ Y2
  {
    int h = tid & 127, part = tid >> 7;
    float acc = 0.f;
    for (int t = part * 256; t < part * 256 + 256; ++t)
      acc += sc[t] * (float)Y2[((size_t)b * 512 + t) * 128 + h];
    if (part == 0) y3[h] = acc;
    __syncthreads();
    if (part == 1) y3[h] += acc;
    __syncthreads();
  }

  // MLP
  if (tid < 128) {
    float a1 = 0.f;
    for (int h2 = 0; h2 < 128; ++h2) a1 += y3[h2] * W1[h2 * 128 + tid];
    hm[tid] = fmaxf(a1 + b1[tid], 0.f);
  }
  __syncthreads();
  if (tid < 128) {
    float a2 = 0.f;
    for (int h2 = 0; h2 < 128; ++h2) a2 += hm[h2] * W2[h2 * 128 + tid];
    a2 = fmaxf(a2 + b2[tid], 0.f);
    float p = a2 * W3[tid];
    #pragma unroll
    for (int m = 1; m < 64; m <<= 1) p += __shfl_xor(p, m, 64);
    if ((tid & 63) == 0) red[4 + (tid >> 6)] = p;
  }
  __syncthreads();
  if (tid == 0) out[b] = red[4] + red[5] + b3[0];
}

// ---------------------------------------------------------------------------
// K5: loss = mean((out - Target)^2)
// ---------------------------------------------------------------------------
__global__ void k5_loss(const float* __restrict__ out, const float* __restrict__ target,
                        float* __restrict__ loss_out)
{
  int l = threadIdx.x;
  float v = 0.f;
  if (l < 32) { float d = out[l] - target[l]; v = d * d; }
  #pragma unroll
  for (int m = 1; m < 64; m <<= 1) v += __shfl_xor(v, m, 64);
  if (l == 0) loss_out[0] = v * (1.f / 32.f);
}

// ---------------------------------------------------------------------------
extern "C" void kernel_launch(void* const* d_in, const int* in_sizes, int n_in,
                              void* d_out, int out_size, void* d_ws, size_t ws_size,
                              hipStream_t stream)
{
  const float* Y      = (const float*)d_in[0];
  const float* Xp     = (const float*)d_in[1];
  const float* Xn     = (const float*)d_in[2];
  const float* Xi     = (const float*)d_in[3];
  const float* Target = (const float*)d_in[4];
  const float* init_c = (const float*)d_in[5];
  const float* init_h = (const float*)d_in[6];
  const float* Wih    = (const float*)d_in[7];
  const float* Whh    = (const float*)d_in[8];
  const float* bih    = (const float*)d_in[9];
  const float* bhh    = (const float*)d_in[10];
  const float* Wc     = (const float*)d_in[11];
  const float* Uc     = (const float*)d_in[12];
  const float* bc     = (const float*)d_in[13];
  const float* Wg     = (const float*)d_in[14];
  const float* Ug     = (const float*)d_in[15];
  const float* bg     = (const float*)d_in[16];
  const float* Wf     = (const float*)d_in[17];
  const float* Uf     = (const float*)d_in[18];
  const float* bf     = (const float*)d_in[19];
  const float* Wo     = (const float*)d_in[20];
  const float* Uo     = (const float*)d_in[21];
  const float* bo     = (const float*)d_in[22];
  const float* Wa     = (const float*)d_in[23];
  const float* Watt   = (const float*)d_in[24];
  const float* batt   = (const float*)d_in[25];
  const float* vatt   = (const float*)d_in[26];
  const float* W1     = (const float*)d_in[27];
  const float* b1     = (const float*)d_in[28];
  const float* W2     = (const float*)d_in[29];
  const float* b2     = (const float*)d_in[30];
  const float* W3     = (const float*)d_in[31];
  const float* b3     = (const float*)d_in[32];

  char* ws = (char*)d_ws;
  _Float16* result = (_Float16*)(ws);                               // 16 MB
  _Float16* candX  = (_Float16*)(ws + ((size_t)16 << 20));          // 16 MB
  _Float16* igX    = (_Float16*)(ws + ((size_t)32 << 20));          // 16 MB
  _Float16* fXp    = (_Float16*)(ws + ((size_t)48 << 20));          // 4 MB
  _Float16* oXp    = (_Float16*)(ws + ((size_t)52 << 20));          // 4 MB
  _Float16* Y2     = (_Float16*)(ws + ((size_t)56 << 20));          // 8 MB
  float* outp = (float*)d_out;

  k1_lstm<<<dim3(68), dim3(512), 0, stream>>>(Y, Xp, Xn, Xi, Wih, Whh, bih, bhh, result);
  k2_gemm<<<dim3(128, 5), dim3(512), 0, stream>>>(result, Wc, Wg, Wf, Wo, candX, igX, fXp, oXp);
  k3_scan<<<dim3(32), dim3(512), 0, stream>>>(Uc, Ug, Uf, Uo, Wa, bc, bg, bf, bo,
                                              init_c, init_h, candX, igX, fXp, oXp, Y2);
  k4_attn<<<dim3(32), dim3(256), 0, stream>>>(Y2, Watt, batt, vatt, W1, b1, W2, b2, W3, b3, outp);
  k5_loss<<<dim3(1), dim3(64), 0, stream>>>(outp, Target, outp + 32);
}

// Round 12
// 1800.902 us; speedup vs baseline: 1.0270x; 1.0270x over previous
//

#include <hip/hip_runtime.h>
#include <hip/hip_fp16.h>

typedef _Float16 half8 __attribute__((ext_vector_type(8)));
typedef float float4_ __attribute__((ext_vector_type(4)));

__device__ __forceinline__ float rcp_(float x) { return __builtin_amdgcn_rcpf(x); }
__device__ __forceinline__ float sigf(float x) { return rcp_(1.f + __expf(-x)); }
__device__ __forceinline__ float tanhf2(float x) {
  x = fminf(fmaxf(x, -15.f), 15.f);
  float e = __expf(-2.f * x);
  return (1.f - e) * rcp_(1.f + e);
}

// ---------------------------------------------------------------------------
// K1: 1088 independent small LSTMs (input dim 1, H=128), 16 seqs per block.
// R8 version (deferred result stores). Unchanged this round.
// ---------------------------------------------------------------------------
__global__ __launch_bounds__(512, 2)
void k1_lstm(const float* __restrict__ Y, const float* __restrict__ Xp,
             const float* __restrict__ Xn, const float* __restrict__ Xi,
             const float* __restrict__ Wih, const float* __restrict__ Whh,
             const float* __restrict__ bih, const float* __restrict__ bhh,
             _Float16* __restrict__ result)
{
  __shared__ float x_lds[16][513];
  __shared__ _Float16 hbuf[2][16][136];

  const int tid  = threadIdx.x;
  const int wv   = tid >> 6;       // wave 0..7
  const int lane = tid & 63;
  const int cl   = lane & 15;
  const int rowg = lane >> 4;      // 0..3
  const int bid  = blockIdx.x;

  const float* xsrc; int slot; int do_mean; int b_out_base;
  if (bid < 2)       { xsrc = Y  + (size_t)(bid * 16) * 512;        slot = 0; do_mean = 0; b_out_base = bid * 16; }
  else if (bid < 4)  { xsrc = Xi + (size_t)((bid - 2) * 16) * 512;  slot = 3; do_mean = 0; b_out_base = (bid - 2) * 16; }
  else if (bid < 36) { xsrc = Xp + (size_t)((bid - 4) * 16) * 512;  slot = 1; do_mean = 1; b_out_base = bid - 4; }
  else               { xsrc = Xn + (size_t)((bid - 36) * 16) * 512; slot = 2; do_mean = 1; b_out_base = bid - 36; }

  // stage x for all 16 sequences
  for (int i = tid; i < 16 * 512; i += 512) {
    int r = i >> 9, t = i & 511;
    x_lds[r][t] = xsrc[r * 512 + t];
  }
  // zero initial h buffer
  for (int i = tid; i < 16 * 136; i += 512) {
    hbuf[0][i / 136][i % 136] = (_Float16)0.f;
  }

  // persistent Whh fragments: gate g, this wave's gate-column cg
  const int cg = wv * 16 + cl;
  half8 bw[4][4];
  #pragma unroll
  for (int g = 0; g < 4; ++g) {
    #pragma unroll
    for (int kc = 0; kc < 4; ++kc) {
      const float* p = Whh + (size_t)(g * 128 + cg) * 128 + kc * 32 + rowg * 8;
      half8 v;
      #pragma unroll
      for (int j = 0; j < 8; ++j) v[j] = (_Float16)p[j];
      bw[g][kc] = v;
    }
  }
  float wih_r[4], bias_r[4];
  #pragma unroll
  for (int g = 0; g < 4; ++g) {
    wih_r[g]  = Wih[g * 128 + cg];
    bias_r[g] = bih[g * 128 + cg] + bhh[g * 128 + cg];
  }

  float c_reg[4] = {0.f, 0.f, 0.f, 0.f};
  float hvp[4] = {0.f, 0.f, 0.f, 0.f};   // deferred-store carry
  float sprev = 0.f;
  __syncthreads();

  for (int t = 0; t < 512; ++t) {
    // deferred global store of step t-1 (retires under this step's MFMA phase)
    if (t > 0) {
      if (!do_mean) {
        #pragma unroll
        for (int i = 0; i < 4; ++i) {
          int b = b_out_base + rowg * 4 + i;
          result[(((size_t)b * 512 + (t - 1)) * 4 + slot) * 128 + cg] = (_Float16)hvp[i];
        }
      } else {
        if (rowg == 0)
          result[(((size_t)b_out_base * 512 + (t - 1)) * 4 + slot) * 128 + cg] = (_Float16)sprev;
      }
    }

    const int cur = t & 1;
    half8 a[4];
    #pragma unroll
    for (int kc = 0; kc < 4; ++kc)
      a[kc] = *(const half8*)&hbuf[cur][cl][kc * 32 + rowg * 8];

    float4_ acc[4];
    #pragma unroll
    for (int g = 0; g < 4; ++g) {
      float4_ z = {0.f, 0.f, 0.f, 0.f};
      #pragma unroll
      for (int kc = 0; kc < 4; ++kc)
        z = __builtin_amdgcn_mfma_f32_16x16x32_f16(a[kc], bw[g][kc], z, 0, 0, 0);
      acc[g] = z;
    }

    float hv[4];
    #pragma unroll
    for (int i = 0; i < 4; ++i) {
      const int row = rowg * 4 + i;
      float x  = x_lds[row][t];
      float ui = acc[0][i] + x * wih_r[0] + bias_r[0];
      float uf = acc[1][i] + x * wih_r[1] + bias_r[1];
      float ug = acc[2][i] + x * wih_r[2] + bias_r[2];
      float uo = acc[3][i] + x * wih_r[3] + bias_r[3];
      float ii = sigf(ui), ff = sigf(uf), gg = tanhf2(ug), oo = sigf(uo);
      float c  = ff * c_reg[i] + ii * gg;
      c_reg[i] = c;
      float h  = oo * tanhf2(c);
      hv[i] = h;
      hbuf[cur ^ 1][row][cg] = (_Float16)h;
    }

    if (!do_mean) {
      #pragma unroll
      for (int i = 0; i < 4; ++i) hvp[i] = hv[i];
    } else {
      float s = hv[0] + hv[1] + hv[2] + hv[3];
      s += __shfl_xor(s, 16, 64);
      s += __shfl_xor(s, 32, 64);
      sprev = s * 0.0625f;
    }
    __syncthreads();
  }

  // final flush (t = 511)
  if (!do_mean) {
    #pragma unroll
    for (int i = 0; i < 4; ++i) {
      int b = b_out_base + rowg * 4 + i;
      result[(((size_t)b * 512 + 511) * 4 + slot) * 128 + cg] = (_Float16)hvp[i];
    }
  } else {
    if (rowg == 0)
      result[(((size_t)b_out_base * 512 + 511) * 4 + slot) * 128 + cg] = (_Float16)sprev;
  }
}

// ---------------------------------------------------------------------------
// K2: input-projection GEMMs for the Mi-LSTM scan (verbatim R1/R6).
// ---------------------------------------------------------------------------
__global__ __launch_bounds__(512, 2)
void k2_gemm(const _Float16* __restrict__ result,
             const float* __restrict__ Wc, const float* __restrict__ Wg,
             const float* __restrict__ Wf, const float* __restrict__ Wo,
             _Float16* __restrict__ candX, _Float16* __restrict__ igX,
             _Float16* __restrict__ fX, _Float16* __restrict__ oX)
{
  __shared__ _Float16 a_lds[128][136];
  __shared__ _Float16 bt_lds[256][136];

  const int tid   = threadIdx.x;
  const int lane  = tid & 63;
  const int wv    = tid >> 6;      // msub
  const int cl    = lane & 15, rowg = lane >> 4;
  const int mtile = blockIdx.x;    // 0..127
  const int role  = blockIdx.y;    // 0 or 1..4

  const int nchunks = (role == 0) ? 4 : 1;
  const int kstream = role - 1;

  float4_ acc[16];
  #pragma unroll
  for (int n = 0; n < 16; ++n) acc[n] = (float4_){0.f, 0.f, 0.f, 0.f};

  for (int ch = 0; ch < nchunks; ++ch) {
    const int koff = (role == 0) ? ch * 128 : kstream * 128;
    for (int i = tid; i < 1024; i += 512) {
      int r = i >> 3, v8 = i & 7;
      half8 val = *(const half8*)&result[((size_t)(mtile * 128 + r)) * 512 + koff + v8 * 8];
      *(half8*)&a_lds[r][v8 * 8] = val;
    }
    for (int i = tid; i < 128 * 256; i += 512) {
      int n = i & 255, kk = i >> 8;
      float w;
      if (role == 0) {
        w = (n < 128) ? Wf[(size_t)(ch * 128 + kk) * 128 + n]
                      : Wo[(size_t)(ch * 128 + kk) * 128 + (n - 128)];
      } else {
        w = (n < 128) ? Wc[(size_t)(kstream * 128 + kk) * 128 + n]
                      : Wg[(size_t)(kstream * 128 + kk) * 128 + (n - 128)];
      }
      bt_lds[n][kk] = (_Float16)w;
    }
    __syncthreads();
    #pragma unroll
    for (int kc = 0; kc < 4; ++kc) {
      half8 a = *(const half8*)&a_lds[wv * 16 + cl][kc * 32 + rowg * 8];
      #pragma unroll
      for (int n = 0; n < 16; ++n) {
        half8 bb = *(const half8*)&bt_lds[n * 16 + cl][kc * 32 + rowg * 8];
        acc[n] = __builtin_amdgcn_mfma_f32_16x16x32_f16(a, bb, acc[n], 0, 0, 0);
      }
    }
    __syncthreads();
  }

  #pragma unroll
  for (int n = 0; n < 16; ++n) {
    int col = n * 16 + cl;
    #pragma unroll
    for (int i = 0; i < 4; ++i) {
      size_t r = (size_t)mtile * 128 + wv * 16 + rowg * 4 + i;
      _Float16 v = (_Float16)acc[n][i];
      if (role == 0) {
        if (col < 128) fX[r * 128 + col] = v;
        else           oX[r * 128 + (col - 128)] = v;
      } else {
        if (col < 128) candX[(r * 4 + kstream) * 128 + col] = v;
        else           igX  [(r * 4 + kstream) * 128 + (col - 128)] = v;
      }
    }
  }
}

// ---------------------------------------------------------------------------
// K3: Mi-LSTM scan — R11 MFMA body + chunked I/O. All global traffic moved to
// chunk boundaries (16 steps/chunk): inputs staged into LDS with uint4 loads,
// h outputs staged in y2s and flushed per chunk. The steady-state 16-step
// loop has ZERO vmem, so its 3 per-step __syncthreads drain nothing (the
// compiler's s_waitcnt vmcnt(0) before s_barrier was serializing a ~900-cyc
// HBM latency into every step). MFMA phase / stage2 / stage3 identical to R11.
// ---------------------------------------------------------------------------
__global__ __launch_bounds__(512, 1)
void k3_scan(const float* __restrict__ Uc, const float* __restrict__ Ug,
             const float* __restrict__ Uf, const float* __restrict__ Uo,
             const float* __restrict__ Wa,
             const float* __restrict__ bc, const float* __restrict__ bg,
             const float* __restrict__ bfv, const float* __restrict__ bov,
             const float* __restrict__ init_c, const float* __restrict__ init_h,
             const _Float16* __restrict__ candX, const _Float16* __restrict__ igX,
             const _Float16* __restrict__ fX, const _Float16* __restrict__ oX,
             _Float16* __restrict__ Y2)
{
  __shared__ __align__(16) unsigned h_pk[64];
  __shared__ __align__(16) unsigned c_pk[64];
  __shared__ float c_f32[128];
  __shared__ __align__(16) float raw[1408];
  __shared__ float part2[2][4];
  __shared__ __align__(16) _Float16 in_c[16 * 512];   // 16 KB
  __shared__ __align__(16) _Float16 in_g[16 * 512];   // 16 KB
  __shared__ __align__(16) _Float16 in_f[16 * 128];   // 4 KB
  __shared__ __align__(16) _Float16 in_o[16 * 128];   // 4 KB
  __shared__ __align__(16) _Float16 y2s[16 * 128];    // 4 KB

  const int tid  = threadIdx.x;
  const int b    = blockIdx.x;
  const int wv   = tid >> 6;
  const int lane = tid & 63;
  const int cl   = lane & 15;
  const int rowg = lane >> 4;

  // gather weight A-fragments: 11 groups of 16 output-cols per wave
  half8 wfrag[11][4];
  #pragma unroll
  for (int gi = 0; gi < 11; ++gi) {
    const int col = (wv * 11 + gi) * 16 + cl;   // global slot 0..1407
    const float* src;
    if (col < 512)       src = Uc + (col >> 7) * 16384 + (col & 127);
    else if (col < 1024) src = Ug + ((col >> 7) - 4) * 16384 + (col & 127);
    else if (col < 1152) src = Uf + (col - 1024);
    else if (col < 1280) src = Uo + (col - 1152);
    else                 src = Wa + (col - 1280);
    #pragma unroll
    for (int kc = 0; kc < 4; ++kc) {
      half8 v;
      #pragma unroll
      for (int j = 0; j < 8; ++j)
        v[j] = (_Float16)src[(kc * 32 + rowg * 8 + j) * 128];
      wfrag[gi][kc] = v;
    }
  }

  float bc_r[4] = {0, 0, 0, 0}, bg_r[4] = {0, 0, 0, 0}, bf_r = 0.f, bo_r = 0.f;
  if (tid < 128) {
    #pragma unroll
    for (int k = 0; k < 4; ++k) { bc_r[k] = bc[k * 128 + tid]; bg_r[k] = bg[k * 128 + tid]; }
    bf_r = bfv[tid]; bo_r = bov[tid];
    c_f32[tid] = init_c[b * 128 + tid];
  }
  if (tid < 64) {
    union { _Float16 h[2]; unsigned u; } hp, cp;
    hp.h[0] = (_Float16)init_h[b * 128 + 2 * tid];
    hp.h[1] = (_Float16)init_h[b * 128 + 2 * tid + 1];
    cp.h[0] = (_Float16)init_c[b * 128 + 2 * tid];
    cp.h[1] = (_Float16)init_c[b * 128 + 2 * tid + 1];
    h_pk[tid] = hp.u;
    c_pk[tid] = cp.u;
  }
  __syncthreads();

  uint4* y2g = (uint4*)Y2;

  for (int chunk = 0; chunk < 32; ++chunk) {
    // flush previous chunk's h (y2s stable since last step's B3)
    if (chunk > 0 && tid < 256)
      y2g[(size_t)b * 8192 + (size_t)(chunk - 1) * 256 + tid] = ((const uint4*)y2s)[tid];
    // stage this chunk's inputs (one HBM round-trip per 16 steps)
    {
      const uint4* c4 = (const uint4*)(candX + ((size_t)b * 512 + chunk * 16) * 512);
      const uint4* g4 = (const uint4*)(igX   + ((size_t)b * 512 + chunk * 16) * 512);
      ((uint4*)in_c)[tid]       = c4[tid];
      ((uint4*)in_c)[tid + 512] = c4[tid + 512];
      ((uint4*)in_g)[tid]       = g4[tid];
      ((uint4*)in_g)[tid + 512] = g4[tid + 512];
      if (tid < 256)
        ((uint4*)in_f)[tid] = ((const uint4*)(fX + ((size_t)b * 512 + chunk * 16) * 128))[tid];
      else
        ((uint4*)in_o)[tid - 256] = ((const uint4*)(oX + ((size_t)b * 512 + chunk * 16) * 128))[tid - 256];
    }
    __syncthreads();   // chunk barrier: drains staging loads + prior flush

    for (int s = 0; s < 16; ++s) {
      // per-step inputs from LDS (overlaps the MFMA phase)
      float cx[4] = {0, 0, 0, 0}, gx[4] = {0, 0, 0, 0}, fx = 0.f, ox = 0.f;
      if (tid < 128) {
        #pragma unroll
        for (int k = 0; k < 4; ++k) {
          cx[k] = (float)in_c[(s * 4 + k) * 128 + tid];
          gx[k] = (float)in_g[(s * 4 + k) * 128 + tid];
        }
        fx = (float)in_f[s * 128 + tid];
        ox = (float)in_o[s * 128 + tid];
      }

      // MFMA phase: raw[g*16 .. g*16+15] = U_group_g · (h or c)
      {
        const uint4* hp4 = (const uint4*)h_pk;
        const uint4* cp4 = (const uint4*)c_pk;
        union { uint4 u; half8 h; } hb[4], cb[4];
        #pragma unroll
        for (int kc = 0; kc < 4; ++kc) {
          hb[kc].u = hp4[kc * 4 + rowg];
          cb[kc].u = cp4[kc * 4 + rowg];
        }
        #pragma unroll
        for (int gi = 0; gi < 11; ++gi) {
          const int g = wv * 11 + gi;
          float4_ acc = {0.f, 0.f, 0.f, 0.f};
          if (g < 80) {
            #pragma unroll
            for (int kc = 0; kc < 4; ++kc)
              acc = __builtin_amdgcn_mfma_f32_16x16x32_f16(wfrag[gi][kc], hb[kc].h, acc, 0, 0, 0);
          } else {
            #pragma unroll
            for (int kc = 0; kc < 4; ++kc)
              acc = __builtin_amdgcn_mfma_f32_16x16x32_f16(wfrag[gi][kc], cb[kc].h, acc, 0, 0, 0);
          }
          if (cl == 0)
            *(float4_*)&raw[g * 16 + rowg * 4] = acc;
        }
      }
      __syncthreads();   // B1

      float l0 = 0.f, l1 = 0.f, l2 = 0.f, l3 = 0.f, fj = 0.f, oj = 0.f;
      if (tid < 128) {
        float cand[4], ig[4];
        #pragma unroll
        for (int k = 0; k < 4; ++k) {
          float uc = cx[k] + raw[k * 128 + tid] + bc_r[k];
          float ui = gx[k] + raw[512 + k * 128 + tid] + bg_r[k];
          cand[k] = tanhf2(uc);
          ig[k]   = sigf(ui);
        }
        l0 = ig[0] * cand[0]; l1 = ig[1] * cand[1];
        l2 = ig[2] * cand[2]; l3 = ig[3] * cand[3];
        float cwa = raw[1280 + tid];
        float p0 = l0 * cwa, p1 = l1 * cwa, p2 = l2 * cwa, p3 = l3 * cwa;
        #pragma unroll
        for (int m = 1; m < 64; m <<= 1) {
          p0 += __shfl_xor(p0, m, 64);
          p1 += __shfl_xor(p1, m, 64);
          p2 += __shfl_xor(p2, m, 64);
          p3 += __shfl_xor(p3, m, 64);
        }
        if ((tid & 63) == 0) {
          part2[tid >> 6][0] = p0; part2[tid >> 6][1] = p1;
          part2[tid >> 6][2] = p2; part2[tid >> 6][3] = p3;
        }
        fj = sigf(fx + raw[1024 + tid] + bf_r);
        oj = sigf(ox + raw[1152 + tid] + bo_r);
      }
      __syncthreads();   // B2

      if (tid < 128) {
        float d0 = part2[0][0] + part2[1][0];
        float d1 = part2[0][1] + part2[1][1];
        float d2 = part2[0][2] + part2[1][2];
        float d3 = part2[0][3] + part2[1][3];
        float mx = fmaxf(fmaxf(d0, d1), fmaxf(d2, d3));
        float e0 = __expf(d0 - mx), e1 = __expf(d1 - mx);
        float e2 = __expf(d2 - mx), e3 = __expf(d3 - mx);
        float inv = rcp_(e0 + e1 + e2 + e3);
        float lmix = (e0 * l0 + e1 * l1 + e2 * l2 + e3 * l3) * inv;
        float c = fj * c_f32[tid] + lmix;
        c_f32[tid] = c;
        float h = oj * tanhf2(c);
        ((_Float16*)h_pk)[tid] = (_Float16)h;
        ((_Float16*)c_pk)[tid] = (_Float16)c;
        y2s[s * 128 + tid] = (_Float16)h;   // staged; flushed at chunk boundary
      }
      __syncthreads();   // B3
    }
  }

  // final flush (chunk 31)
  if (tid < 256)
    y2g[(size_t)b * 8192 + (size_t)31 * 256 + tid] = ((const uint4*)y2s)[tid];
}

// ---------------------------------------------------------------------------
// K4: temporal attention + MLP head, one block per b (verbatim R1/R6).
// ---------------------------------------------------------------------------
__global__ __launch_bounds__(256, 1)
void k4_attn(const _Float16* __restrict__ Y2,
             const float* __restrict__ Watt, const float* __restrict__ batt,
             const float* __restrict__ vatt,
             const float* __restrict__ W1, const float* __restrict__ b1,
             const float* __restrict__ W2, const float* __restrict__ b2,
             const float* __restrict__ W3, const float* __restrict__ b3,
             float* __restrict__ out)
{
  __shared__ _Float16 wt_lds[128][136];
  __shared__ float sc[512];
  __shared__ float red[8];
  __shared__ float y3[128];
  __shared__ float hm[128];

  const int tid = threadIdx.x;
  const int b   = blockIdx.x;
  const int lane = tid & 63, wv = tid >> 6;
  const int cl = lane & 15, rowg = lane >> 4;

  for (int i = tid; i < 128 * 128; i += 256) {
    int h = i >> 7, j = i & 127;
    wt_lds[j][h] = (_Float16)Watt[h * 128 + j];
  }
  __syncthreads();

  half8 bw[8][4];
  #pragma unroll
  for (int n = 0; n < 8; ++n)
    #pragma unroll
    for (int kc = 0; kc < 4; ++kc)
      bw[n][kc] = *(const half8*)&wt_lds[n * 16 + cl][kc * 32 + rowg * 8];
  float battr[8], vattr[8];
  #pragma unroll
  for (int n = 0; n < 8; ++n) { battr[n] = batt[n * 16 + cl]; vattr[n] = vatt[n * 16 + cl]; }

  for (int mt = wv * 8; mt < wv * 8 + 8; ++mt) {
    half8 a[4];
    #pragma unroll
    for (int kc = 0; kc < 4; ++kc)
      a[kc] = *(const half8*)&Y2[((size_t)b * 512 + mt * 16 + cl) * 128 + kc * 32 + rowg * 8];
    float sp[4] = {0.f, 0.f, 0.f, 0.f};
    #pragma unroll
    for (int n = 0; n < 8; ++n) {
      float4_ acc = {0.f, 0.f, 0.f, 0.f};
      #pragma unroll
      for (int kc = 0; kc < 4; ++kc)
        acc = __builtin_amdgcn_mfma_f32_16x16x32_f16(a[kc], bw[n][kc], acc, 0, 0, 0);
      #pragma unroll
      for (int i = 0; i < 4; ++i)
        sp[i] += tanhf2(acc[i] + battr[n]) * vattr[n];
    }
    #pragma unroll
    for (int i = 0; i < 4; ++i) {
      #pragma unroll
      for (int m = 1; m < 16; m <<= 1) sp[i] += __shfl_xor(sp[i], m, 64);
    }
    if (cl == 0) {
      #pragma unroll
      for (int i = 0; i < 4; ++i) sc[mt * 16 + rowg * 4 + i] = sp[i];
    }
  }
  __syncthreads();

  // softmax over 512 scores
  float v0 = sc[tid], v1 = sc[tid + 256];
  float mx = fmaxf(v0, v1);
  #pragma unroll
  for (int m = 1; m < 64; m <<= 1) mx = fmaxf(mx, __shfl_xor(mx, m, 64));
  if (lane == 0) red[wv] = mx;
  __syncthreads();
  mx = fmaxf(fmaxf(red[0], red[1]), fmaxf(red[2], red[3]));
  float e0 = __expf(v0 - mx), e1 = __expf(v1 - mx);
  float s = e0 + e1;
  #pragma unroll
  for (int m = 1; m < 64; m <<= 1) s += __shfl_xor(s, m, 64);
  __syncthreads();
  if (lane == 0) red[wv] = s;
  __syncthreads();
  float inv = rcp_(red[0] + red[1] + red[2] + red[3]);
  sc[tid] = e0 * inv;
  sc[tid + 256] = e1 * inv;
  __syncthreads();

  // Y3 = attw @ Y2
  {
    int h = tid & 127, part = tid >> 7;
    float acc = 0.f;
    for (int t = part * 256; t < part * 256 + 256; ++t)
      acc += sc[t] * (float)Y2[((size_t)b * 512 + t) * 128 + h];
    if (part == 0) y3[h] = acc;
    __syncthreads();
    if (part == 1) y3[h] += acc;
    __syncthreads();
  }

  // MLP
  if (tid < 128) {
    float a1 = 0.f;
    for (int h2 = 0; h2 < 128; ++h2) a1 += y3[h2] * W1[h2 * 128 + tid];
    hm[tid] = fmaxf(a1 + b1[tid], 0.f);
  }
  __syncthreads();
  if (tid < 128) {
    float a2 = 0.f;
    for (int h2 = 0; h2 < 128; ++h2) a2 += hm[h2] * W2[h2 * 128 + tid];
    a2 = fmaxf(a2 + b2[tid], 0.f);
    float p = a2 * W3[tid];
    #pragma unroll
    for (int m = 1; m < 64; m <<= 1) p += __shfl_xor(p, m, 64);
    if ((tid & 63) == 0) red[4 + (tid >> 6)] = p;
  }
  __syncthreads();
  if (tid == 0) out[b] = red[4] + red[5] + b3[0];
}

// ---------------------------------------------------------------------------
// K5: loss = mean((out - Target)^2)
// ---------------------------------------------------------------------------
__global__ void k5_loss(const float* __restrict__ out, const float* __restrict__ target,
                        float* __restrict__ loss_out)
{
  int l = threadIdx.x;
  float v = 0.f;
  if (l < 32) { float d = out[l] - target[l]; v = d * d; }
  #pragma unroll
  for (int m = 1; m < 64; m <<= 1) v += __shfl_xor(v, m, 64);
  if (l == 0) loss_out[0] = v * (1.f / 32.f);
}

// ---------------------------------------------------------------------------
extern "C" void kernel_launch(void* const* d_in, const int* in_sizes, int n_in,
                              void* d_out, int out_size, void* d_ws, size_t ws_size,
                              hipStream_t stream)
{
  const float* Y      = (const float*)d_in[0];
  const float* Xp     = (const float*)d_in[1];
  const float* Xn     = (const float*)d_in[2];
  const float* Xi     = (const float*)d_in[3];
  const float* Target = (const float*)d_in[4];
  const float* init_c = (const float*)d_in[5];
  const float* init_h = (const float*)d_in[6];
  const float* Wih    = (const float*)d_in[7];
  const float* Whh    = (const float*)d_in[8];
  const float* bih    = (const float*)d_in[9];
  const float* bhh    = (const float*)d_in[10];
  const float* Wc     = (const float*)d_in[11];
  const float* Uc     = (const float*)d_in[12];
  const float* bc     = (const float*)d_in[13];
  const float* Wg     = (const float*)d_in[14];
  const float* Ug     = (const float*)d_in[15];
  const float* bg     = (const float*)d_in[16];
  const float* Wf     = (const float*)d_in[17];
  const float* Uf     = (const float*)d_in[18];
  const float* bf     = (const float*)d_in[19];
  const float* Wo     = (const float*)d_in[20];
  const float* Uo     = (const float*)d_in[21];
  const float* bo     = (const float*)d_in[22];
  const float* Wa     = (const float*)d_in[23];
  const float* Watt   = (const float*)d_in[24];
  const float* batt   = (const float*)d_in[25];
  const float* vatt   = (const float*)d_in[26];
  const float* W1     = (const float*)d_in[27];
  const float* b1     = (const float*)d_in[28];
  const float* W2     = (const float*)d_in[29];
  const float* b2     = (const float*)d_in[30];
  const float* W3     = (const float*)d_in[31];
  const float* b3     = (const float*)d_in[32];

  char* ws = (char*)d_ws;
  _Float16* result = (_Float16*)(ws);                               // 16 MB
  _Float16* candX  = (_Float16*)(ws + ((size_t)16 << 20));          // 16 MB
  _Float16* igX    = (_Float16*)(ws + ((size_t)32 << 20));          // 16 MB
  _Float16* fXp    = (_Float16*)(ws + ((size_t)48 << 20));          // 4 MB
  _Float16* oXp    = (_Float16*)(ws + ((size_t)52 << 20));          // 4 MB
  _Float16* Y2     = (_Float16*)(ws + ((size_t)56 << 20));          // 8 MB
  float* outp = (float*)d_out;

  k1_lstm<<<dim3(68), dim3(512), 0, stream>>>(Y, Xp, Xn, Xi, Wih, Whh, bih, bhh, result);
  k2_gemm<<<dim3(128, 5), dim3(512), 0, stream>>>(result, Wc, Wg, Wf, Wo, candX, igX, fXp, oXp);
  k3_scan<<<dim3(32), dim3(512), 0, stream>>>(Uc, Ug, Uf, Uo, Wa, bc, bg, bf, bo,
                                              init_c, init_h, candX, igX, fXp, oXp, Y2);
  k4_attn<<<dim3(32), dim3(256), 0, stream>>>(Y2, Watt, batt, vatt, W1, b1, W2, b2, W3, b3, outp);
  k5_loss<<<dim3(1), dim3(64), 0, stream>>>(outp, Target, outp + 32);
}

// Round 13
// 1771.876 us; speedup vs baseline: 1.0438x; 1.0164x over previous
//

#include <hip/hip_runtime.h>
#include <hip/hip_fp16.h>

typedef _Float16 half8 __attribute__((ext_vector_type(8)));
typedef float float4_ __attribute__((ext_vector_type(4)));

__device__ __forceinline__ float rcp_(float x) { return __builtin_amdgcn_rcpf(x); }
__device__ __forceinline__ float sigf(float x) { return rcp_(1.f + __expf(-x)); }
__device__ __forceinline__ float tanhf2(float x) {
  x = fminf(fmaxf(x, -15.f), 15.f);
  float e = __expf(-2.f * x);
  return (1.f - e) * rcp_(1.f + e);
}
__device__ __forceinline__ float2 up2(unsigned u) {
  union { unsigned u; _Float16 h[2]; } cv; cv.u = u;
  return make_float2((float)cv.h[0], (float)cv.h[1]);
}

// ---------------------------------------------------------------------------
// K1: 1088 independent small LSTMs (input dim 1, H=128), 16 seqs per block.
// R8 version (deferred result stores). Unchanged this round.
// ---------------------------------------------------------------------------
__global__ __launch_bounds__(512, 2)
void k1_lstm(const float* __restrict__ Y, const float* __restrict__ Xp,
             const float* __restrict__ Xn, const float* __restrict__ Xi,
             const float* __restrict__ Wih, const float* __restrict__ Whh,
             const float* __restrict__ bih, const float* __restrict__ bhh,
             _Float16* __restrict__ result)
{
  __shared__ float x_lds[16][513];
  __shared__ _Float16 hbuf[2][16][136];

  const int tid  = threadIdx.x;
  const int wv   = tid >> 6;       // wave 0..7
  const int lane = tid & 63;
  const int cl   = lane & 15;
  const int rowg = lane >> 4;      // 0..3
  const int bid  = blockIdx.x;

  const float* xsrc; int slot; int do_mean; int b_out_base;
  if (bid < 2)       { xsrc = Y  + (size_t)(bid * 16) * 512;        slot = 0; do_mean = 0; b_out_base = bid * 16; }
  else if (bid < 4)  { xsrc = Xi + (size_t)((bid - 2) * 16) * 512;  slot = 3; do_mean = 0; b_out_base = (bid - 2) * 16; }
  else if (bid < 36) { xsrc = Xp + (size_t)((bid - 4) * 16) * 512;  slot = 1; do_mean = 1; b_out_base = bid - 4; }
  else               { xsrc = Xn + (size_t)((bid - 36) * 16) * 512; slot = 2; do_mean = 1; b_out_base = bid - 36; }

  // stage x for all 16 sequences
  for (int i = tid; i < 16 * 512; i += 512) {
    int r = i >> 9, t = i & 511;
    x_lds[r][t] = xsrc[r * 512 + t];
  }
  // zero initial h buffer
  for (int i = tid; i < 16 * 136; i += 512) {
    hbuf[0][i / 136][i % 136] = (_Float16)0.f;
  }

  // persistent Whh fragments: gate g, this wave's gate-column cg
  const int cg = wv * 16 + cl;
  half8 bw[4][4];
  #pragma unroll
  for (int g = 0; g < 4; ++g) {
    #pragma unroll
    for (int kc = 0; kc < 4; ++kc) {
      const float* p = Whh + (size_t)(g * 128 + cg) * 128 + kc * 32 + rowg * 8;
      half8 v;
      #pragma unroll
      for (int j = 0; j < 8; ++j) v[j] = (_Float16)p[j];
      bw[g][kc] = v;
    }
  }
  float wih_r[4], bias_r[4];
  #pragma unroll
  for (int g = 0; g < 4; ++g) {
    wih_r[g]  = Wih[g * 128 + cg];
    bias_r[g] = bih[g * 128 + cg] + bhh[g * 128 + cg];
  }

  float c_reg[4] = {0.f, 0.f, 0.f, 0.f};
  float hvp[4] = {0.f, 0.f, 0.f, 0.f};   // deferred-store carry
  float sprev = 0.f;
  __syncthreads();

  for (int t = 0; t < 512; ++t) {
    // deferred global store of step t-1 (retires under this step's MFMA phase)
    if (t > 0) {
      if (!do_mean) {
        #pragma unroll
        for (int i = 0; i < 4; ++i) {
          int b = b_out_base + rowg * 4 + i;
          result[(((size_t)b * 512 + (t - 1)) * 4 + slot) * 128 + cg] = (_Float16)hvp[i];
        }
      } else {
        if (rowg == 0)
          result[(((size_t)b_out_base * 512 + (t - 1)) * 4 + slot) * 128 + cg] = (_Float16)sprev;
      }
    }

    const int cur = t & 1;
    half8 a[4];
    #pragma unroll
    for (int kc = 0; kc < 4; ++kc)
      a[kc] = *(const half8*)&hbuf[cur][cl][kc * 32 + rowg * 8];

    float4_ acc[4];
    #pragma unroll
    for (int g = 0; g < 4; ++g) {
      float4_ z = {0.f, 0.f, 0.f, 0.f};
      #pragma unroll
      for (int kc = 0; kc < 4; ++kc)
        z = __builtin_amdgcn_mfma_f32_16x16x32_f16(a[kc], bw[g][kc], z, 0, 0, 0);
      acc[g] = z;
    }

    float hv[4];
    #pragma unroll
    for (int i = 0; i < 4; ++i) {
      const int row = rowg * 4 + i;
      float x  = x_lds[row][t];
      float ui = acc[0][i] + x * wih_r[0] + bias_r[0];
      float uf = acc[1][i] + x * wih_r[1] + bias_r[1];
      float ug = acc[2][i] + x * wih_r[2] + bias_r[2];
      float uo = acc[3][i] + x * wih_r[3] + bias_r[3];
      float ii = sigf(ui), ff = sigf(uf), gg = tanhf2(ug), oo = sigf(uo);
      float c  = ff * c_reg[i] + ii * gg;
      c_reg[i] = c;
      float h  = oo * tanhf2(c);
      hv[i] = h;
      hbuf[cur ^ 1][row][cg] = (_Float16)h;
    }

    if (!do_mean) {
      #pragma unroll
      for (int i = 0; i < 4; ++i) hvp[i] = hv[i];
    } else {
      float s = hv[0] + hv[1] + hv[2] + hv[3];
      s += __shfl_xor(s, 16, 64);
      s += __shfl_xor(s, 32, 64);
      sprev = s * 0.0625f;
    }
    __syncthreads();
  }

  // final flush (t = 511)
  if (!do_mean) {
    #pragma unroll
    for (int i = 0; i < 4; ++i) {
      int b = b_out_base + rowg * 4 + i;
      result[(((size_t)b * 512 + 511) * 4 + slot) * 128 + cg] = (_Float16)hvp[i];
    }
  } else {
    if (rowg == 0)
      result[(((size_t)b_out_base * 512 + 511) * 4 + slot) * 128 + cg] = (_Float16)sprev;
  }
}

// ---------------------------------------------------------------------------
// K2: input-projection GEMMs for the Mi-LSTM scan (verbatim R1/R6).
// ---------------------------------------------------------------------------
__global__ __launch_bounds__(512, 2)
void k2_gemm(const _Float16* __restrict__ result,
             const float* __restrict__ Wc, const float* __restrict__ Wg,
             const float* __restrict__ Wf, const float* __restrict__ Wo,
             _Float16* __restrict__ candX, _Float16* __restrict__ igX,
             _Float16* __restrict__ fX, _Float16* __restrict__ oX)
{
  __shared__ _Float16 a_lds[128][136];
  __shared__ _Float16 bt_lds[256][136];

  const int tid   = threadIdx.x;
  const int lane  = tid & 63;
  const int wv    = tid >> 6;      // msub
  const int cl    = lane & 15, rowg = lane >> 4;
  const int mtile = blockIdx.x;    // 0..127
  const int role  = blockIdx.y;    // 0 or 1..4

  const int nchunks = (role == 0) ? 4 : 1;
  const int kstream = role - 1;

  float4_ acc[16];
  #pragma unroll
  for (int n = 0; n < 16; ++n) acc[n] = (float4_){0.f, 0.f, 0.f, 0.f};

  for (int ch = 0; ch < nchunks; ++ch) {
    const int koff = (role == 0) ? ch * 128 : kstream * 128;
    for (int i = tid; i < 1024; i += 512) {
      int r = i >> 3, v8 = i & 7;
      half8 val = *(const half8*)&result[((size_t)(mtile * 128 + r)) * 512 + koff + v8 * 8];
      *(half8*)&a_lds[r][v8 * 8] = val;
    }
    for (int i = tid; i < 128 * 256; i += 512) {
      int n = i & 255, kk = i >> 8;
      float w;
      if (role == 0) {
        w = (n < 128) ? Wf[(size_t)(ch * 128 + kk) * 128 + n]
                      : Wo[(size_t)(ch * 128 + kk) * 128 + (n - 128)];
      } else {
        w = (n < 128) ? Wc[(size_t)(kstream * 128 + kk) * 128 + n]
                      : Wg[(size_t)(kstream * 128 + kk) * 128 + (n - 128)];
      }
      bt_lds[n][kk] = (_Float16)w;
    }
    __syncthreads();
    #pragma unroll
    for (int kc = 0; kc < 4; ++kc) {
      half8 a = *(const half8*)&a_lds[wv * 16 + cl][kc * 32 + rowg * 8];
      #pragma unroll
      for (int n = 0; n < 16; ++n) {
        half8 bb = *(const half8*)&bt_lds[n * 16 + cl][kc * 32 + rowg * 8];
        acc[n] = __builtin_amdgcn_mfma_f32_16x16x32_f16(a, bb, acc[n], 0, 0, 0);
      }
    }
    __syncthreads();
  }

  #pragma unroll
  for (int n = 0; n < 16; ++n) {
    int col = n * 16 + cl;
    #pragma unroll
    for (int i = 0; i < 4; ++i) {
      size_t r = (size_t)mtile * 128 + wv * 16 + rowg * 4 + i;
      _Float16 v = (_Float16)acc[n][i];
      if (role == 0) {
        if (col < 128) fX[r * 128 + col] = v;
        else           oX[r * 128 + (col - 128)] = v;
      } else {
        if (col < 128) candX[(r * 4 + kstream) * 128 + col] = v;
        else           igX  [(r * 4 + kstream) * 128 + (col - 128)] = v;
      }
    }
  }
}

// ---------------------------------------------------------------------------
// K3: Mi-LSTM scan — R12 chunked zero-vmem loop + MFMA phase, with stage2+3
// FUSED into wave 0 (lane owns j=2*lane, 2*lane+1): the k-softmax reduce is
// wave-internal shfl (part2 round-trip and B3 eliminated -> 2 barriers/step),
// c carried in wave-0 registers (c_f32 gone). This fused-stage arithmetic
// passed in R7 (1.335e-4); R7's regression was its in-loop global prefetch,
// which the chunked LDS staging has removed.
// ---------------------------------------------------------------------------
__global__ __launch_bounds__(512, 1)
void k3_scan(const float* __restrict__ Uc, const float* __restrict__ Ug,
             const float* __restrict__ Uf, const float* __restrict__ Uo,
             const float* __restrict__ Wa,
             const float* __restrict__ bc, const float* __restrict__ bg,
             const float* __restrict__ bfv, const float* __restrict__ bov,
             const float* __restrict__ init_c, const float* __restrict__ init_h,
             const _Float16* __restrict__ candX, const _Float16* __restrict__ igX,
             const _Float16* __restrict__ fX, const _Float16* __restrict__ oX,
             _Float16* __restrict__ Y2)
{
  __shared__ __align__(16) unsigned h_pk[64];
  __shared__ __align__(16) unsigned c_pk[64];
  __shared__ __align__(16) float raw[1408];
  __shared__ __align__(16) _Float16 in_c[16 * 512];   // 16 KB
  __shared__ __align__(16) _Float16 in_g[16 * 512];   // 16 KB
  __shared__ __align__(16) _Float16 in_f[16 * 128];   // 4 KB
  __shared__ __align__(16) _Float16 in_o[16 * 128];   // 4 KB
  __shared__ __align__(16) _Float16 y2s[16 * 128];    // 4 KB

  const int tid  = threadIdx.x;
  const int b    = blockIdx.x;
  const int wv   = tid >> 6;
  const int lane = tid & 63;
  const int cl   = lane & 15;
  const int rowg = lane >> 4;

  // gather weight A-fragments: 11 groups of 16 output-cols per wave
  half8 wfrag[11][4];
  #pragma unroll
  for (int gi = 0; gi < 11; ++gi) {
    const int col = (wv * 11 + gi) * 16 + cl;   // global slot 0..1407
    const float* src;
    if (col < 512)       src = Uc + (col >> 7) * 16384 + (col & 127);
    else if (col < 1024) src = Ug + ((col >> 7) - 4) * 16384 + (col & 127);
    else if (col < 1152) src = Uf + (col - 1024);
    else if (col < 1280) src = Uo + (col - 1152);
    else                 src = Wa + (col - 1280);
    #pragma unroll
    for (int kc = 0; kc < 4; ++kc) {
      half8 v;
      #pragma unroll
      for (int j = 0; j < 8; ++j)
        v[j] = (_Float16)src[(kc * 32 + rowg * 8 + j) * 128];
      wfrag[gi][kc] = v;
    }
  }

  // wave-0 per-lane state: lane owns output dims j = 2*tid, 2*tid+1
  float c0 = 0.f, c1 = 0.f;
  float2 bc2[4], bg2[4], bf2 = {0.f, 0.f}, bo2 = {0.f, 0.f};
  if (tid < 64) {
    float2 ci = *(const float2*)&init_c[b * 128 + 2 * tid];
    float2 hi = *(const float2*)&init_h[b * 128 + 2 * tid];
    c0 = ci.x; c1 = ci.y;
    union { _Float16 h[2]; unsigned u; } hu, cu;
    hu.h[0] = (_Float16)hi.x; hu.h[1] = (_Float16)hi.y;
    cu.h[0] = (_Float16)ci.x; cu.h[1] = (_Float16)ci.y;
    h_pk[tid] = hu.u; c_pk[tid] = cu.u;
    #pragma unroll
    for (int k = 0; k < 4; ++k) {
      bc2[k] = *(const float2*)&bc[k * 128 + 2 * tid];
      bg2[k] = *(const float2*)&bg[k * 128 + 2 * tid];
    }
    bf2 = *(const float2*)&bfv[2 * tid];
    bo2 = *(const float2*)&bov[2 * tid];
  }
  __syncthreads();

  uint4* y2g = (uint4*)Y2;

  for (int chunk = 0; chunk < 32; ++chunk) {
    // flush previous chunk's h (y2s stable since last step's barrier)
    if (chunk > 0 && tid < 256)
      y2g[(size_t)b * 8192 + (size_t)(chunk - 1) * 256 + tid] = ((const uint4*)y2s)[tid];
    // stage this chunk's inputs (one HBM round-trip per 16 steps)
    {
      const uint4* c4 = (const uint4*)(candX + ((size_t)b * 512 + chunk * 16) * 512);
      const uint4* g4 = (const uint4*)(igX   + ((size_t)b * 512 + chunk * 16) * 512);
      ((uint4*)in_c)[tid]       = c4[tid];
      ((uint4*)in_c)[tid + 512] = c4[tid + 512];
      ((uint4*)in_g)[tid]       = g4[tid];
      ((uint4*)in_g)[tid + 512] = g4[tid + 512];
      if (tid < 256)
        ((uint4*)in_f)[tid] = ((const uint4*)(fX + ((size_t)b * 512 + chunk * 16) * 128))[tid];
      else
        ((uint4*)in_o)[tid - 256] = ((const uint4*)(oX + ((size_t)b * 512 + chunk * 16) * 128))[tid - 256];
    }
    __syncthreads();   // chunk barrier: drains staging loads + prior flush

    for (int s = 0; s < 16; ++s) {
      // MFMA phase: raw[g*16 .. g*16+15] = U_group_g · (h or c)
      {
        const uint4* hp4 = (const uint4*)h_pk;
        const uint4* cp4 = (const uint4*)c_pk;
        union { uint4 u; half8 h; } hb[4], cb[4];
        #pragma unroll
        for (int kc = 0; kc < 4; ++kc) {
          hb[kc].u = hp4[kc * 4 + rowg];
          cb[kc].u = cp4[kc * 4 + rowg];
        }
        #pragma unroll
        for (int gi = 0; gi < 11; ++gi) {
          const int g = wv * 11 + gi;
          float4_ acc = {0.f, 0.f, 0.f, 0.f};
          if (g < 80) {
            #pragma unroll
            for (int kc = 0; kc < 4; ++kc)
              acc = __builtin_amdgcn_mfma_f32_16x16x32_f16(wfrag[gi][kc], hb[kc].h, acc, 0, 0, 0);
          } else {
            #pragma unroll
            for (int kc = 0; kc < 4; ++kc)
              acc = __builtin_amdgcn_mfma_f32_16x16x32_f16(wfrag[gi][kc], cb[kc].h, acc, 0, 0, 0);
          }
          if (cl == 0)
            *(float4_*)&raw[g * 16 + rowg * 4] = acc;
        }
      }
      __syncthreads();   // B1: raw ready

      if (tid < 64) {
        float2 cxv[4], gxv[4];
        #pragma unroll
        for (int k = 0; k < 4; ++k) {
          cxv[k] = up2(((const unsigned*)in_c)[(s * 4 + k) * 64 + tid]);
          gxv[k] = up2(((const unsigned*)in_g)[(s * 4 + k) * 64 + tid]);
        }
        float2 fxv = up2(((const unsigned*)in_f)[s * 64 + tid]);
        float2 oxv = up2(((const unsigned*)in_o)[s * 64 + tid]);

        float2 cwa = *(const float2*)&raw[1280 + 2 * tid];
        float l0[4], l1[4], p[4];
        #pragma unroll
        for (int k = 0; k < 4; ++k) {
          float2 rc = *(const float2*)&raw[k * 128 + 2 * tid];
          float2 rg = *(const float2*)&raw[512 + k * 128 + 2 * tid];
          float ca0 = tanhf2(cxv[k].x + rc.x + bc2[k].x);
          float ca1 = tanhf2(cxv[k].y + rc.y + bc2[k].y);
          float g0  = sigf(gxv[k].x + rg.x + bg2[k].x);
          float g1  = sigf(gxv[k].y + rg.y + bg2[k].y);
          l0[k] = g0 * ca0; l1[k] = g1 * ca1;
          p[k]  = l0[k] * cwa.x + l1[k] * cwa.y;
        }
        float2 rf = *(const float2*)&raw[1024 + 2 * tid];
        float2 ro = *(const float2*)&raw[1152 + 2 * tid];
        float f0 = sigf(fxv.x + rf.x + bf2.x), f1 = sigf(fxv.y + rf.y + bf2.y);
        float o0 = sigf(oxv.x + ro.x + bo2.x), o1 = sigf(oxv.y + ro.y + bo2.y);

        #pragma unroll
        for (int m = 1; m < 64; m <<= 1) {
          p[0] += __shfl_xor(p[0], m, 64);
          p[1] += __shfl_xor(p[1], m, 64);
          p[2] += __shfl_xor(p[2], m, 64);
          p[3] += __shfl_xor(p[3], m, 64);
        }
        float mx = fmaxf(fmaxf(p[0], p[1]), fmaxf(p[2], p[3]));
        float e0 = __expf(p[0] - mx), e1 = __expf(p[1] - mx);
        float e2 = __expf(p[2] - mx), e3 = __expf(p[3] - mx);
        float inv = rcp_(e0 + e1 + e2 + e3);
        float lm0 = (e0 * l0[0] + e1 * l0[1] + e2 * l0[2] + e3 * l0[3]) * inv;
        float lm1 = (e0 * l1[0] + e1 * l1[1] + e2 * l1[2] + e3 * l1[3]) * inv;
        c0 = f0 * c0 + lm0;
        c1 = f1 * c1 + lm1;
        float h0 = o0 * tanhf2(c0), h1 = o1 * tanhf2(c1);
        union { _Float16 h[2]; unsigned u; } hu, cu;
        hu.h[0] = (_Float16)h0; hu.h[1] = (_Float16)h1;
        cu.h[0] = (_Float16)c0; cu.h[1] = (_Float16)c1;
        h_pk[tid] = hu.u;
        c_pk[tid] = cu.u;
        ((unsigned*)y2s)[s * 64 + tid] = hu.u;   // staged; flushed at chunk boundary
      }
      __syncthreads();   // B2: h/c ready for next step
    }
  }

  // final flush (chunk 31)
  if (tid < 256)
    y2g[(size_t)b * 8192 + (size_t)31 * 256 + tid] = ((const uint4*)y2s)[tid];
}

// ---------------------------------------------------------------------------
// K4: temporal attention + MLP head, one block per b (verbatim R1/R6).
// ---------------------------------------------------------------------------
__global__ __launch_bounds__(256, 1)
void k4_attn(const _Float16* __restrict__ Y2,
             const float* __restrict__ Watt, const float* __restrict__ batt,
             const float* __restrict__ vatt,
             const float* __restrict__ W1, const float* __restrict__ b1,
             const float* __restrict__ W2, const float* __restrict__ b2,
             const float* __restrict__ W3, const float* __restrict__ b3,
             float* __restrict__ out)
{
  __shared__ _Float16 wt_lds[128][136];
  __shared__ float sc[512];
  __shared__ float red[8];
  __shared__ float y3[128];
  __shared__ float hm[128];

  const int tid = threadIdx.x;
  const int b   = blockIdx.x;
  const int lane = tid & 63, wv = tid >> 6;
  const int cl = lane & 15, rowg = lane >> 4;

  for (int i = tid; i < 128 * 128; i += 256) {
    int h = i >> 7, j = i & 127;
    wt_lds[j][h] = (_Float16)Watt[h * 128 + j];
  }
  __syncthreads();

  half8 bw[8][4];
  #pragma unroll
  for (int n = 0; n < 8; ++n)
    #pragma unroll
    for (int kc = 0; kc < 4; ++kc)
      bw[n][kc] = *(const half8*)&wt_lds[n * 16 + cl][kc * 32 + rowg * 8];
  float battr[8], vattr[8];
  #pragma unroll
  for (int n = 0; n < 8; ++n) { battr[n] = batt[n * 16 + cl]; vattr[n] = vatt[n * 16 + cl]; }

  for (int mt = wv * 8; mt < wv * 8 + 8; ++mt) {
    half8 a[4];
    #pragma unroll
    for (int kc = 0; kc < 4; ++kc)
      a[kc] = *(const half8*)&Y2[((size_t)b * 512 + mt * 16 + cl) * 128 + kc * 32 + rowg * 8];
    float sp[4] = {0.f, 0.f, 0.f, 0.f};
    #pragma unroll
    for (int n = 0; n < 8; ++n) {
      float4_ acc = {0.f, 0.f, 0.f, 0.f};
      #pragma unroll
      for (int kc = 0; kc < 4; ++kc)
        acc = __builtin_amdgcn_mfma_f32_16x16x32_f16(a[kc], bw[n][kc], acc, 0, 0, 0);
      #pragma unroll
      for (int i = 0; i < 4; ++i)
        sp[i] += tanhf2(acc[i] + battr[n]) * vattr[n];
    }
    #pragma unroll
    for (int i = 0; i < 4; ++i) {
      #pragma unroll
      for (int m = 1; m < 16; m <<= 1) sp[i] += __shfl_xor(sp[i], m, 64);
    }
    if (cl == 0) {
      #pragma unroll
      for (int i = 0; i < 4; ++i) sc[mt * 16 + rowg * 4 + i] = sp[i];
    }
  }
  __syncthreads();

  // softmax over 512 scores
  float v0 = sc[tid], v1 = sc[tid + 256];
  float mx = fmaxf(v0, v1);
  #pragma unroll
  for (int m = 1; m < 64; m <<= 1) mx = fmaxf(mx, __shfl_xor(mx, m, 64));
  if (lane == 0) red[wv] = mx;
  __syncthreads();
  mx = fmaxf(fmaxf(red[0], red[1]), fmaxf(red[2], red[3]));
  float e0 = __expf(v0 - mx), e1 = __expf(v1 - mx);
  float s = e0 + e1;
  #pragma unroll
  for (int m = 1; m < 64; m <<= 1) s += __shfl_xor(s, m, 64);
  __syncthreads();
  if (lane == 0) red[wv] = s;
  __syncthreads();
  float inv = rcp_(red[0] + red[1] + red[2] + red[3]);
  sc[tid] = e0 * inv;
  sc[tid + 256] = e1 * inv;
  __syncthreads();

  // Y3 = attw @ Y2
  {
    int h = tid & 127, part = tid >> 7;
    float acc = 0.f;
    for (int t = part * 256; t < part * 256 + 256; ++t)
      acc += sc[t] * (float)Y2[((size_t)b * 512 + t) * 128 + h];
    if (part == 0) y3[h] = acc;
    __syncthreads();
    if (part == 1) y3[h] += acc;
    __syncthreads();
  }

  // MLP
  if (tid < 128) {
    float a1 = 0.f;
    for (int h2 = 0; h2 < 128; ++h2) a1 += y3[h2] * W1[h2 * 128 + tid];
    hm[tid] = fmaxf(a1 + b1[tid], 0.f);
  }
  __syncthreads();
  if (tid < 128) {
    float a2 = 0.f;
    for (int h2 = 0; h2 < 128; ++h2) a2 += hm[h2] * W2[h2 * 128 + tid];
    a2 = fmaxf(a2 + b2[tid], 0.f);
    float p = a2 * W3[tid];
    #pragma unroll
    for (int m = 1; m < 64; m <<= 1) p += __shfl_xor(p, m, 64);
    if ((tid & 63) == 0) red[4 + (tid >> 6)] = p;
  }
  __syncthreads();
  if (tid == 0) out[b] = red[4] + red[5] + b3[0];
}

// ---------------------------------------------------------------------------
// K5: loss = mean((out - Target)^2)
// ---------------------------------------------------------------------------
__global__ void k5_loss(const float* __restrict__ out, const float* __restrict__ target,
                        float* __restrict__ loss_out)
{
  int l = threadIdx.x;
  float v = 0.f;
  if (l < 32) { float d = out[l] - target[l]; v = d * d; }
  #pragma unroll
  for (int m = 1; m < 64; m <<= 1) v += __shfl_xor(v, m, 64);
  if (l == 0) loss_out[0] = v * (1.f / 32.f);
}

// ---------------------------------------------------------------------------
extern "C" void kernel_launch(void* const* d_in, const int* in_sizes, int n_in,
                              void* d_out, int out_size, void* d_ws, size_t ws_size,
                              hipStream_t stream)
{
  const float* Y      = (const float*)d_in[0];
  const float* Xp     = (const float*)d_in[1];
  const float* Xn     = (const float*)d_in[2];
  const float* Xi     = (const float*)d_in[3];
  const float* Target = (const float*)d_in[4];
  const float* init_c = (const float*)d_in[5];
  const float* init_h = (const float*)d_in[6];
  const float* Wih    = (const float*)d_in[7];
  const float* Whh    = (const float*)d_in[8];
  const float* bih    = (const float*)d_in[9];
  const float* bhh    = (const float*)d_in[10];
  const float* Wc     = (const float*)d_in[11];
  const float* Uc     = (const float*)d_in[12];
  const float* bc     = (const float*)d_in[13];
  const float* Wg     = (const float*)d_in[14];
  const float* Ug     = (const float*)d_in[15];
  const float* bg     = (const float*)d_in[16];
  const float* Wf     = (const float*)d_in[17];
  const float* Uf     = (const float*)d_in[18];
  const float* bf     = (const float*)d_in[19];
  const float* Wo     = (const float*)d_in[20];
  const float* Uo     = (const float*)d_in[21];
  const float* bo     = (const float*)d_in[22];
  const float* Wa     = (const float*)d_in[23];
  const float* Watt   = (const float*)d_in[24];
  const float* batt   = (const float*)d_in[25];
  const float* vatt   = (const float*)d_in[26];
  const float* W1     = (const float*)d_in[27];
  const float* b1     = (const float*)d_in[28];
  const float* W2     = (const float*)d_in[29];
  const float* b2     = (const float*)d_in[30];
  const float* W3     = (const float*)d_in[31];
  const float* b3     = (const float*)d_in[32];

  char* ws = (char*)d_ws;
  _Float16* result = (_Float16*)(ws);                               // 16 MB
  _Float16* candX  = (_Float16*)(ws + ((size_t)16 << 20));          // 16 MB
  _Float16* igX    = (_Float16*)(ws + ((size_t)32 << 20));          // 16 MB
  _Float16* fXp    = (_Float16*)(ws + ((size_t)48 << 20));          // 4 MB
  _Float16* oXp    = (_Float16*)(ws + ((size_t)52 << 20));          // 4 MB
  _Float16* Y2     = (_Float16*)(ws + ((size_t)56 << 20));          // 8 MB
  float* outp = (float*)d_out;

  k1_lstm<<<dim3(68), dim3(512), 0, stream>>>(Y, Xp, Xn, Xi, Wih, Whh, bih, bhh, result);
  k2_gemm<<<dim3(128, 5), dim3(512), 0, stream>>>(result, Wc, Wg, Wf, Wo, candX, igX, fXp, oXp);
  k3_scan<<<dim3(32), dim3(512), 0, stream>>>(Uc, Ug, Uf, Uo, Wa, bc, bg, bf, bo,
                                              init_c, init_h, candX, igX, fXp, oXp, Y2);
  k4_attn<<<dim3(32), dim3(256), 0, stream>>>(Y2, Watt, batt, vatt, W1, b1, W2, b2, W3, b3, outp);
  k5_loss<<<dim3(1), dim3(64), 0, stream>>>(outp, Target, outp + 32);
}

// Round 15
// 1649.603 us; speedup vs baseline: 1.1212x; 1.0741x over previous
//

#include <hip/hip_runtime.h>
#include <hip/hip_fp16.h>

typedef _Float16 half8 __attribute__((ext_vector_type(8)));
typedef _Float16 half2_ __attribute__((ext_vector_type(2)));
typedef float float4_ __attribute__((ext_vector_type(4)));

__device__ __forceinline__ float rcp_(float x) { return __builtin_amdgcn_rcpf(x); }
__device__ __forceinline__ float sigf(float x) { return rcp_(1.f + __expf(-x)); }
__device__ __forceinline__ float tanhf2(float x) {
  x = fminf(fmaxf(x, -15.f), 15.f);
  float e = __expf(-2.f * x);
  return (1.f - e) * rcp_(1.f + e);
}

// v_dot2_f32_f16 via builtin (register-allocator-friendly). Fallback: asm.
#if __has_builtin(__builtin_amdgcn_fdot2)
__device__ __forceinline__ float dot2f(float acc, unsigned w, unsigned h) {
  union { unsigned u; half2_ v; } cw, ch;
  cw.u = w; ch.u = h;
  return __builtin_amdgcn_fdot2(cw.v, ch.v, acc, false);
}
#else
__device__ __forceinline__ float dot2f(float acc, unsigned w, unsigned h) {
  asm("v_dot2_f32_f16 %0, %1, %2, %0" : "+v"(acc) : "v"(w), "v"(h));
  return acc;
}
#endif
#define DOT2F16(acc, w, h) acc = dot2f(acc, w, h)

// ---------------------------------------------------------------------------
// K1: 1088 independent small LSTMs (input dim 1, H=128), 16 seqs per block.
// R8/R10 version (deferred result stores). Unchanged this round.
// ---------------------------------------------------------------------------
__global__ __launch_bounds__(512, 2)
void k1_lstm(const float* __restrict__ Y, const float* __restrict__ Xp,
             const float* __restrict__ Xn, const float* __restrict__ Xi,
             const float* __restrict__ Wih, const float* __restrict__ Whh,
             const float* __restrict__ bih, const float* __restrict__ bhh,
             _Float16* __restrict__ result)
{
  __shared__ float x_lds[16][513];
  __shared__ _Float16 hbuf[2][16][136];

  const int tid  = threadIdx.x;
  const int wv   = tid >> 6;       // wave 0..7
  const int lane = tid & 63;
  const int cl   = lane & 15;
  const int rowg = lane >> 4;      // 0..3
  const int bid  = blockIdx.x;

  const float* xsrc; int slot; int do_mean; int b_out_base;
  if (bid < 2)       { xsrc = Y  + (size_t)(bid * 16) * 512;        slot = 0; do_mean = 0; b_out_base = bid * 16; }
  else if (bid < 4)  { xsrc = Xi + (size_t)((bid - 2) * 16) * 512;  slot = 3; do_mean = 0; b_out_base = (bid - 2) * 16; }
  else if (bid < 36) { xsrc = Xp + (size_t)((bid - 4) * 16) * 512;  slot = 1; do_mean = 1; b_out_base = bid - 4; }
  else               { xsrc = Xn + (size_t)((bid - 36) * 16) * 512; slot = 2; do_mean = 1; b_out_base = bid - 36; }

  // stage x for all 16 sequences
  for (int i = tid; i < 16 * 512; i += 512) {
    int r = i >> 9, t = i & 511;
    x_lds[r][t] = xsrc[r * 512 + t];
  }
  // zero initial h buffer
  for (int i = tid; i < 16 * 136; i += 512) {
    hbuf[0][i / 136][i % 136] = (_Float16)0.f;
  }

  // persistent Whh fragments: gate g, this wave's gate-column cg
  const int cg = wv * 16 + cl;
  half8 bw[4][4];
  #pragma unroll
  for (int g = 0; g < 4; ++g) {
    #pragma unroll
    for (int kc = 0; kc < 4; ++kc) {
      const float* p = Whh + (size_t)(g * 128 + cg) * 128 + kc * 32 + rowg * 8;
      half8 v;
      #pragma unroll
      for (int j = 0; j < 8; ++j) v[j] = (_Float16)p[j];
      bw[g][kc] = v;
    }
  }
  float wih_r[4], bias_r[4];
  #pragma unroll
  for (int g = 0; g < 4; ++g) {
    wih_r[g]  = Wih[g * 128 + cg];
    bias_r[g] = bih[g * 128 + cg] + bhh[g * 128 + cg];
  }

  float c_reg[4] = {0.f, 0.f, 0.f, 0.f};
  float hvp[4] = {0.f, 0.f, 0.f, 0.f};   // deferred-store carry
  float sprev = 0.f;
  __syncthreads();

  for (int t = 0; t < 512; ++t) {
    // deferred global store of step t-1 (retires under this step's MFMA phase)
    if (t > 0) {
      if (!do_mean) {
        #pragma unroll
        for (int i = 0; i < 4; ++i) {
          int b = b_out_base + rowg * 4 + i;
          result[(((size_t)b * 512 + (t - 1)) * 4 + slot) * 128 + cg] = (_Float16)hvp[i];
        }
      } else {
        if (rowg == 0)
          result[(((size_t)b_out_base * 512 + (t - 1)) * 4 + slot) * 128 + cg] = (_Float16)sprev;
      }
    }

    const int cur = t & 1;
    half8 a[4];
    #pragma unroll
    for (int kc = 0; kc < 4; ++kc)
      a[kc] = *(const half8*)&hbuf[cur][cl][kc * 32 + rowg * 8];

    float4_ acc[4];
    #pragma unroll
    for (int g = 0; g < 4; ++g) {
      float4_ z = {0.f, 0.f, 0.f, 0.f};
      #pragma unroll
      for (int kc = 0; kc < 4; ++kc)
        z = __builtin_amdgcn_mfma_f32_16x16x32_f16(a[kc], bw[g][kc], z, 0, 0, 0);
      acc[g] = z;
    }

    float hv[4];
    #pragma unroll
    for (int i = 0; i < 4; ++i) {
      const int row = rowg * 4 + i;
      float x  = x_lds[row][t];
      float ui = acc[0][i] + x * wih_r[0] + bias_r[0];
      float uf = acc[1][i] + x * wih_r[1] + bias_r[1];
      float ug = acc[2][i] + x * wih_r[2] + bias_r[2];
      float uo = acc[3][i] + x * wih_r[3] + bias_r[3];
      float ii = sigf(ui), ff = sigf(uf), gg = tanhf2(ug), oo = sigf(uo);
      float c  = ff * c_reg[i] + ii * gg;
      c_reg[i] = c;
      float h  = oo * tanhf2(c);
      hv[i] = h;
      hbuf[cur ^ 1][row][cg] = (_Float16)h;
    }

    if (!do_mean) {
      #pragma unroll
      for (int i = 0; i < 4; ++i) hvp[i] = hv[i];
    } else {
      float s = hv[0] + hv[1] + hv[2] + hv[3];
      s += __shfl_xor(s, 16, 64);
      s += __shfl_xor(s, 32, 64);
      sprev = s * 0.0625f;
    }
    __syncthreads();
  }

  // final flush (t = 511)
  if (!do_mean) {
    #pragma unroll
    for (int i = 0; i < 4; ++i) {
      int b = b_out_base + rowg * 4 + i;
      result[(((size_t)b * 512 + 511) * 4 + slot) * 128 + cg] = (_Float16)hvp[i];
    }
  } else {
    if (rowg == 0)
      result[(((size_t)b_out_base * 512 + 511) * 4 + slot) * 128 + cg] = (_Float16)sprev;
  }
}

// ---------------------------------------------------------------------------
// K2: input-projection GEMMs for the Mi-LSTM scan (verbatim R1/R6/R10).
// ---------------------------------------------------------------------------
__global__ __launch_bounds__(512, 2)
void k2_gemm(const _Float16* __restrict__ result,
             const float* __restrict__ Wc, const float* __restrict__ Wg,
             const float* __restrict__ Wf, const float* __restrict__ Wo,
             _Float16* __restrict__ candX, _Float16* __restrict__ igX,
             _Float16* __restrict__ fX, _Float16* __restrict__ oX)
{
  __shared__ _Float16 a_lds[128][136];
  __shared__ _Float16 bt_lds[256][136];

  const int tid   = threadIdx.x;
  const int lane  = tid & 63;
  const int wv    = tid >> 6;      // msub
  const int cl    = lane & 15, rowg = lane >> 4;
  const int mtile = blockIdx.x;    // 0..127
  const int role  = blockIdx.y;    // 0 or 1..4

  const int nchunks = (role == 0) ? 4 : 1;
  const int kstream = role - 1;

  float4_ acc[16];
  #pragma unroll
  for (int n = 0; n < 16; ++n) acc[n] = (float4_){0.f, 0.f, 0.f, 0.f};

  for (int ch = 0; ch < nchunks; ++ch) {
    const int koff = (role == 0) ? ch * 128 : kstream * 128;
    for (int i = tid; i < 1024; i += 512) {
      int r = i >> 3, v8 = i & 7;
      half8 val = *(const half8*)&result[((size_t)(mtile * 128 + r)) * 512 + koff + v8 * 8];
      *(half8*)&a_lds[r][v8 * 8] = val;
    }
    for (int i = tid; i < 128 * 256; i += 512) {
      int n = i & 255, kk = i >> 8;
      float w;
      if (role == 0) {
        w = (n < 128) ? Wf[(size_t)(ch * 128 + kk) * 128 + n]
                      : Wo[(size_t)(ch * 128 + kk) * 128 + (n - 128)];
      } else {
        w = (n < 128) ? Wc[(size_t)(kstream * 128 + kk) * 128 + n]
                      : Wg[(size_t)(kstream * 128 + kk) * 128 + (n - 128)];
      }
      bt_lds[n][kk] = (_Float16)w;
    }
    __syncthreads();
    #pragma unroll
    for (int kc = 0; kc < 4; ++kc) {
      half8 a = *(const half8*)&a_lds[wv * 16 + cl][kc * 32 + rowg * 8];
      #pragma unroll
      for (int n = 0; n < 16; ++n) {
        half8 bb = *(const half8*)&bt_lds[n * 16 + cl][kc * 32 + rowg * 8];
        acc[n] = __builtin_amdgcn_mfma_f32_16x16x32_f16(a, bb, acc[n], 0, 0, 0);
      }
    }
    __syncthreads();
  }

  #pragma unroll
  for (int n = 0; n < 16; ++n) {
    int col = n * 16 + cl;
    #pragma unroll
    for (int i = 0; i < 4; ++i) {
      size_t r = (size_t)mtile * 128 + wv * 16 + rowg * 4 + i;
      _Float16 v = (_Float16)acc[n][i];
      if (role == 0) {
        if (col < 128) fX[r * 128 + col] = v;
        else           oX[r * 128 + (col - 128)] = v;
      } else {
        if (col < 128) candX[(r * 4 + kstream) * 128 + col] = v;
        else           igX  [(r * 4 + kstream) * 128 + (col - 128)] = v;
      }
    }
  }
}

// ---------------------------------------------------------------------------
// K3: Mi-LSTM scan — R10 body verbatim (3 barriers/step, stage2 on tid<128,
// loop-top prefetch, deferred Y2 store, in-kernel PRELOAD, fdot2 engine).
// ONE change vs R10: amdgpu_waves_per_eu(2,2) — caps the allocator's
// occupancy target at 2 waves/EU (= our actual 8 waves/CU), so it may use up
// to 256 arch VGPRs and keep the 192 packed-weight words out of AGPRs
// (eliminating the per-dot v_accvgpr_read tax that VALUBusy implies).
// ---------------------------------------------------------------------------
#define PRELOAD(arr, sbase)                                                 \
  {                                                                         \
    const int s = tid + sbase;                                              \
    const float* src; float mul = 1.f;                                      \
    if (s < 512)       src = Uc + (s >> 7) * 16384 + (s & 127);             \
    else if (s < 1024) src = Ug + ((s >> 7) - 4) * 16384 + (s & 127);       \
    else if (s < 1152) src = Uf + (s - 1024);                               \
    else if (s < 1280) src = Uo + (s - 1152);                               \
    else if (s < 1408) src = Wa + (s - 1280);                               \
    else             { src = Wa; mul = 0.f; }                               \
    _Pragma("unroll")                                                       \
    for (int d = 0; d < 64; ++d) {                                          \
      union { _Float16 h[2]; unsigned u; } cv;                              \
      cv.h[0] = (_Float16)(src[(2 * d) * 128] * mul);                       \
      cv.h[1] = (_Float16)(src[(2 * d + 1) * 128] * mul);                   \
      arr[d] = cv.u;                                                        \
    }                                                                       \
  }

__global__ __launch_bounds__(512)
__attribute__((amdgpu_waves_per_eu(2, 2)))
void k3_scan(const float* __restrict__ Uc, const float* __restrict__ Ug,
             const float* __restrict__ Uf, const float* __restrict__ Uo,
             const float* __restrict__ Wa,
             const float* __restrict__ bc, const float* __restrict__ bg,
             const float* __restrict__ bfv, const float* __restrict__ bov,
             const float* __restrict__ init_c, const float* __restrict__ init_h,
             const _Float16* __restrict__ candX, const _Float16* __restrict__ igX,
             const _Float16* __restrict__ fX, const _Float16* __restrict__ oX,
             _Float16* __restrict__ Y2)
{
  __shared__ __align__(16) unsigned h_pk[64];
  __shared__ __align__(16) unsigned c_pk[64];
  __shared__ float c_f32[128];
  __shared__ float raw[1536];
  __shared__ float part2[2][4];

  const int tid = threadIdx.x;
  const int b   = blockIdx.x;

  unsigned wpk0[64], wpk1[64], wpk2[64];
  PRELOAD(wpk0, 0)
  PRELOAD(wpk1, 512)
  PRELOAD(wpk2, 1024)

  float bc_r[4] = {0, 0, 0, 0}, bg_r[4] = {0, 0, 0, 0}, bf_r = 0.f, bo_r = 0.f;
  if (tid < 128) {
    #pragma unroll
    for (int k = 0; k < 4; ++k) { bc_r[k] = bc[k * 128 + tid]; bg_r[k] = bg[k * 128 + tid]; }
    bf_r = bfv[tid]; bo_r = bov[tid];
    c_f32[tid] = init_c[b * 128 + tid];
  }
  if (tid < 64) {
    union { _Float16 h[2]; unsigned u; } hp, cp;
    hp.h[0] = (_Float16)init_h[b * 128 + 2 * tid];
    hp.h[1] = (_Float16)init_h[b * 128 + 2 * tid + 1];
    cp.h[0] = (_Float16)init_c[b * 128 + 2 * tid];
    cp.h[1] = (_Float16)init_c[b * 128 + 2 * tid + 1];
    h_pk[tid] = hp.u;
    c_pk[tid] = cp.u;
  }
  __syncthreads();

  const int slot3 = tid + 1024;
  float hprev = 0.f;   // deferred Y2 carry (tid<128)

  for (int t = 0; t < 512; ++t) {
    // deferred Y2 store of step t-1 (retires under this step's dot phase)
    if (t > 0 && tid < 128)
      Y2[((size_t)b * 512 + (t - 1)) * 128 + tid] = (_Float16)hprev;

    // prefetch precomputed input projections (hidden under the dot phase)
    float cx[4] = {0, 0, 0, 0}, gx[4] = {0, 0, 0, 0}, fx = 0.f, ox = 0.f;
    if (tid < 128) {
      size_t r = (size_t)b * 512 + t;
      #pragma unroll
      for (int k = 0; k < 4; ++k) {
        cx[k] = (float)candX[(r * 4 + k) * 128 + tid];
        gx[k] = (float)igX  [(r * 4 + k) * 128 + tid];
      }
      fx = (float)fX[r * 128 + tid];
      ox = (float)oX[r * 128 + tid];
    }

    float a1 = 0.f, a2 = 0.f, a3 = 0.f;
    {
      const uint4* hp4 = (const uint4*)h_pk;
      if (tid < 256 || tid >= 384) {
        #pragma unroll
        for (int g = 0; g < 16; ++g) {
          uint4 hv = hp4[g];
          DOT2F16(a1, wpk0[4*g+0], hv.x); DOT2F16(a2, wpk1[4*g+0], hv.x); DOT2F16(a3, wpk2[4*g+0], hv.x);
          DOT2F16(a1, wpk0[4*g+1], hv.y); DOT2F16(a2, wpk1[4*g+1], hv.y); DOT2F16(a3, wpk2[4*g+1], hv.y);
          DOT2F16(a1, wpk0[4*g+2], hv.z); DOT2F16(a2, wpk1[4*g+2], hv.z); DOT2F16(a3, wpk2[4*g+2], hv.z);
          DOT2F16(a1, wpk0[4*g+3], hv.w); DOT2F16(a2, wpk1[4*g+3], hv.w); DOT2F16(a3, wpk2[4*g+3], hv.w);
        }
      } else {  // waves 4,5: third slot contracts against c (cWa)
        const uint4* cp4 = (const uint4*)c_pk;
        #pragma unroll
        for (int g = 0; g < 16; ++g) {
          uint4 hv = hp4[g]; uint4 hc = cp4[g];
          DOT2F16(a1, wpk0[4*g+0], hv.x); DOT2F16(a2, wpk1[4*g+0], hv.x); DOT2F16(a3, wpk2[4*g+0], hc.x);
          DOT2F16(a1, wpk0[4*g+1], hv.y); DOT2F16(a2, wpk1[4*g+1], hv.y); DOT2F16(a3, wpk2[4*g+1], hc.y);
          DOT2F16(a1, wpk0[4*g+2], hv.z); DOT2F16(a2, wpk1[4*g+2], hv.z); DOT2F16(a3, wpk2[4*g+2], hc.z);
          DOT2F16(a1, wpk0[4*g+3], hv.w); DOT2F16(a2, wpk1[4*g+3], hv.w); DOT2F16(a3, wpk2[4*g+3], hc.w);
        }
      }
    }
    raw[tid]       = a1;
    raw[tid + 512] = a2;
    raw[slot3]     = a3;
    __syncthreads();   // B1

    float l0 = 0.f, l1 = 0.f, l2 = 0.f, l3 = 0.f, fj = 0.f, oj = 0.f;
    if (tid < 128) {
      float cand[4], ig[4];
      #pragma unroll
      for (int k = 0; k < 4; ++k) {
        float uc = cx[k] + raw[k * 128 + tid] + bc_r[k];
        float ui = gx[k] + raw[512 + k * 128 + tid] + bg_r[k];
        cand[k] = tanhf2(uc);
        ig[k]   = sigf(ui);
      }
      l0 = ig[0] * cand[0]; l1 = ig[1] * cand[1];
      l2 = ig[2] * cand[2]; l3 = ig[3] * cand[3];
      float cwa = raw[1280 + tid];
      float p0 = l0 * cwa, p1 = l1 * cwa, p2 = l2 * cwa, p3 = l3 * cwa;
      #pragma unroll
      for (int m = 1; m < 64; m <<= 1) {
        p0 += __shfl_xor(p0, m, 64);
        p1 += __shfl_xor(p1, m, 64);
        p2 += __shfl_xor(p2, m, 64);
        p3 += __shfl_xor(p3, m, 64);
      }
      if ((tid & 63) == 0) {
        part2[tid >> 6][0] = p0; part2[tid >> 6][1] = p1;
        part2[tid >> 6][2] = p2; part2[tid >> 6][3] = p3;
      }
      fj = sigf(fx + raw[1024 + tid] + bf_r);
      oj = sigf(ox + raw[1152 + tid] + bo_r);
    }
    __syncthreads();   // B2

    if (tid < 128) {
      float d0 = part2[0][0] + part2[1][0];
      float d1 = part2[0][1] + part2[1][1];
      float d2 = part2[0][2] + part2[1][2];
      float d3 = part2[0][3] + part2[1][3];
      float mx = fmaxf(fmaxf(d0, d1), fmaxf(d2, d3));
      float e0 = __expf(d0 - mx), e1 = __expf(d1 - mx);
      float e2 = __expf(d2 - mx), e3 = __expf(d3 - mx);
      float inv = rcp_(e0 + e1 + e2 + e3);
      float lmix = (e0 * l0 + e1 * l1 + e2 * l2 + e3 * l3) * inv;
      float c = fj * c_f32[tid] + lmix;
      c_f32[tid] = c;
      float h = oj * tanhf2(c);
      ((_Float16*)h_pk)[tid] = (_Float16)h;
      ((_Float16*)c_pk)[tid] = (_Float16)c;
      hprev = h;        // Y2 store deferred to next loop top
    }
    __syncthreads();   // B3
  }

  // final flush (t = 511)
  if (tid < 128)
    Y2[((size_t)b * 512 + 511) * 128 + tid] = (_Float16)hprev;
}

// ---------------------------------------------------------------------------
// K4: temporal attention + MLP head, one block per b (verbatim R1/R6/R10).
// ---------------------------------------------------------------------------
__global__ __launch_bounds__(256, 1)
void k4_attn(const _Float16* __restrict__ Y2,
             const float* __restrict__ Watt, const float* __restrict__ batt,
             const float* __restrict__ vatt,
             const float* __restrict__ W1, const float* __restrict__ b1,
             const float* __restrict__ W2, const float* __restrict__ b2,
             const float* __restrict__ W3, const float* __restrict__ b3,
             float* __restrict__ out)
{
  __shared__ _Float16 wt_lds[128][136];
  __shared__ float sc[512];
  __shared__ float red[8];
  __shared__ float y3[128];
  __shared__ float hm[128];

  const int tid = threadIdx.x;
  const int b   = blockIdx.x;
  const int lane = tid & 63, wv = tid >> 6;
  const int cl = lane & 15, rowg = lane >> 4;

  for (int i = tid; i < 128 * 128; i += 256) {
    int h = i >> 7, j = i & 127;
    wt_lds[j][h] = (_Float16)Watt[h * 128 + j];
  }
  __syncthreads();

  half8 bw[8][4];
  #pragma unroll
  for (int n = 0; n < 8; ++n)
    #pragma unroll
    for (int kc = 0; kc < 4; ++kc)
      bw[n][kc] = *(const half8*)&wt_lds[n * 16 + cl][kc * 32 + rowg * 8];
  float battr[8], vattr[8];
  #pragma unroll
  for (int n = 0; n < 8; ++n) { battr[n] = batt[n * 16 + cl]; vattr[n] = vatt[n * 16 + cl]; }

  for (int mt = wv * 8; mt < wv * 8 + 8; ++mt) {
    half8 a[4];
    #pragma unroll
    for (int kc = 0; kc < 4; ++kc)
      a[kc] = *(const half8*)&Y2[((size_t)b * 512 + mt * 16 + cl) * 128 + kc * 32 + rowg * 8];
    float sp[4] = {0.f, 0.f, 0.f, 0.f};
    #pragma unroll
    for (int n = 0; n < 8; ++n) {
      float4_ acc = {0.f, 0.f, 0.f, 0.f};
      #pragma unroll
      for (int kc = 0; kc < 4; ++kc)
        acc = __builtin_amdgcn_mfma_f32_16x16x32_f16(a[kc], bw[n][kc], acc, 0, 0, 0);
      #pragma unroll
      for (int i = 0; i < 4; ++i)
        sp[i] += tanhf2(acc[i] + battr[n]) * vattr[n];
    }
    #pragma unroll
    for (int i = 0; i < 4; ++i) {
      #pragma unroll
      for (int m = 1; m < 16; m <<= 1) sp[i] += __shfl_xor(sp[i], m, 64);
    }
    if (cl == 0) {
      #pragma unroll
      for (int i = 0; i < 4; ++i) sc[mt * 16 + rowg * 4 + i] = sp[i];
    }
  }
  __syncthreads();

  // softmax over 512 scores
  float v0 = sc[tid], v1 = sc[tid + 256];
  float mx = fmaxf(v0, v1);
  #pragma unroll
  for (int m = 1; m < 64; m <<= 1) mx = fmaxf(mx, __shfl_xor(mx, m, 64));
  if (lane == 0) red[wv] = mx;
  __syncthreads();
  mx = fmaxf(fmaxf(red[0], red[1]), fmaxf(red[2], red[3]));
  float e0 = __expf(v0 - mx), e1 = __expf(v1 - mx);
  float s = e0 + e1;
  #pragma unroll
  for (int m = 1; m < 64; m <<= 1) s += __shfl_xor(s, m, 64);
  __syncthreads();
  if (lane == 0) red[wv] = s;
  __syncthreads();
  float inv = rcp_(red[0] + red[1] + red[2] + red[3]);
  sc[tid] = e0 * inv;
  sc[tid + 256] = e1 * inv;
  __syncthreads();

  // Y3 = attw @ Y2
  {
    int h = tid & 127, part = tid >> 7;
    float acc = 0.f;
    for (int t = part * 256; t < part * 256 + 256; ++t)
      acc += sc[t] * (float)Y2[((size_t)b * 512 + t) * 128 + h];
    if (part == 0) y3[h] = acc;
    __syncthreads();
    if (part == 1) y3[h] += acc;
    __syncthreads();
  }

  // MLP
  if (tid < 128) {
    float a1 = 0.f;
    for (int h2 = 0; h2 < 128; ++h2) a1 += y3[h2] * W1[h2 * 128 + tid];
    hm[tid] = fmaxf(a1 + b1[tid], 0.f);
  }
  __syncthreads();
  if (tid < 128) {
    float a2 = 0.f;
    for (int h2 = 0; h2 < 128; ++h2) a2 += hm[h2] * W2[h2 * 128 + tid];
    a2 = fmaxf(a2 + b2[tid], 0.f);
    float p = a2 * W3[tid];
    #pragma unroll
    for (int m = 1; m < 64; m <<= 1) p += __shfl_xor(p, m, 64);
    if ((tid & 63) == 0) red[4 + (tid >> 6)] = p;
  }
  __syncthreads();
  if (tid == 0) out[b] = red[4] + red[5] + b3[0];
}

// ---------------------------------------------------------------------------
// K5: loss = mean((out - Target)^2)
// ---------------------------------------------------------------------------
__global__ void k5_loss(const float* __restrict__ out, const float* __restrict__ target,
                        float* __restrict__ loss_out)
{
  int l = threadIdx.x;
  float v = 0.f;
  if (l < 32) { float d = out[l] - target[l]; v = d * d; }
  #pragma unroll
  for (int m = 1; m < 64; m <<= 1) v += __shfl_xor(v, m, 64);
  if (l == 0) loss_out[0] = v * (1.f / 32.f);
}

// ---------------------------------------------------------------------------
extern "C" void kernel_launch(void* const* d_in, const int* in_sizes, int n_in,
                              void* d_out, int out_size, void* d_ws, size_t ws_size,
                              hipStream_t stream)
{
  const float* Y      = (const float*)d_in[0];
  const float* Xp     = (const float*)d_in[1];
  const float* Xn     = (const float*)d_in[2];
  const float* Xi     = (const float*)d_in[3];
  const float* Target = (const float*)d_in[4];
  const float* init_c = (const float*)d_in[5];
  const float* init_h = (const float*)d_in[6];
  const float* Wih    = (const float*)d_in[7];
  const float* Whh    = (const float*)d_in[8];
  const float* bih    = (const float*)d_in[9];
  const float* bhh    = (const float*)d_in[10];
  const float* Wc     = (const float*)d_in[11];
  const float* Uc     = (const float*)d_in[12];
  const float* bc     = (const float*)d_in[13];
  const float* Wg     = (const float*)d_in[14];
  const float* Ug     = (const float*)d_in[15];
  const float* bg     = (const float*)d_in[16];
  const float* Wf     = (const float*)d_in[17];
  const float* Uf     = (const float*)d_in[18];
  const float* bf     = (const float*)d_in[19];
  const float* Wo     = (const float*)d_in[20];
  const float* Uo     = (const float*)d_in[21];
  const float* bo     = (const float*)d_in[22];
  const float* Wa     = (const float*)d_in[23];
  const float* Watt   = (const float*)d_in[24];
  const float* batt   = (const float*)d_in[25];
  const float* vatt   = (const float*)d_in[26];
  const float* W1     = (const float*)d_in[27];
  const float* b1     = (const float*)d_in[28];
  const float* W2     = (const float*)d_in[29];
  const float* b2     = (const float*)d_in[30];
  const float* W3     = (const float*)d_in[31];
  const float* b3     = (const float*)d_in[32];

  char* ws = (char*)d_ws;
  _Float16* result = (_Float16*)(ws);                               // 16 MB
  _Float16* candX  = (_Float16*)(ws + ((size_t)16 << 20));          // 16 MB
  _Float16* igX    = (_Float16*)(ws + ((size_t)32 << 20));          // 16 MB
  _Float16* fXp    = (_Float16*)(ws + ((size_t)48 << 20));          // 4 MB
  _Float16* oXp    = (_Float16*)(ws + ((size_t)52 << 20));          // 4 MB
  _Float16* Y2     = (_Float16*)(ws + ((size_t)56 << 20));          // 8 MB
  float* outp = (float*)d_out;

  k1_lstm<<<dim3(68), dim3(512), 0, stream>>>(Y, Xp, Xn, Xi, Wih, Whh, bih, bhh, result);
  k2_gemm<<<dim3(128, 5), dim3(512), 0, stream>>>(result, Wc, Wg, Wf, Wo, candX, igX, fXp, oXp);
  k3_scan<<<dim3(32), dim3(512), 0, stream>>>(Uc, Ug, Uf, Uo, Wa, bc, bg, bf, bo,
                                              init_c, init_h, candX, igX, fXp, oXp, Y2);
  k4_attn<<<dim3(32), dim3(256), 0, stream>>>(Y2, Watt, batt, vatt, W1, b1, W2, b2, W3, b3, outp);
  k5_loss<<<dim3(1), dim3(64), 0, stream>>>(outp, Target, outp + 32);
}